// Round 1
// baseline (1051.157 us; speedup 1.0000x reference)
//
#include <hip/hip_runtime.h>
#include <stdint.h>

typedef __attribute__((ext_vector_type(8))) short s16x8;
typedef __attribute__((ext_vector_type(4))) float f32x4;

#define DM 1024
#define TOK 512

static __device__ __forceinline__ float bf2f(short u) {
  union { unsigned int i; float f; } x;
  x.i = ((unsigned int)(unsigned short)u) << 16;
  return x.f;
}
static __device__ __forceinline__ short f2bf(float f) {
  union { float f; unsigned int i; } x; x.f = f;
  unsigned int r = x.i + 0x7FFFu + ((x.i >> 16) & 1u);
  return (short)(r >> 16);
}
static __device__ __forceinline__ f32x4 fzero4() {
  f32x4 z; z[0]=0.f; z[1]=0.f; z[2]=0.f; z[3]=0.f; return z;
}

// ---------------- cast relu(x) f32 -> bf16 ----------------
__global__ __launch_bounds__(256) void cast_relu_kernel(const float* __restrict__ x,
                                                        short* __restrict__ xb) {
  size_t i = ((size_t)blockIdx.x * 256 + threadIdx.x) * 8;
  float4 v0 = *(const float4*)(x + i);
  float4 v1 = *(const float4*)(x + i + 4);
  s16x8 o;
  o[0] = f2bf(fmaxf(v0.x, 0.f)); o[1] = f2bf(fmaxf(v0.y, 0.f));
  o[2] = f2bf(fmaxf(v0.z, 0.f)); o[3] = f2bf(fmaxf(v0.w, 0.f));
  o[4] = f2bf(fmaxf(v1.x, 0.f)); o[5] = f2bf(fmaxf(v1.y, 0.f));
  o[6] = f2bf(fmaxf(v1.z, 0.f)); o[7] = f2bf(fmaxf(v1.w, 0.f));
  *(s16x8*)(xb + i) = o;
}

// ---------------- masked means (v and q) ----------------
// grid (DM/256, B, 2); block 256
__global__ __launch_bounds__(256) void mean_kernel(const float* __restrict__ v,
                                                   const float* __restrict__ q,
                                                   const float* __restrict__ vmask,
                                                   const float* __restrict__ qmask,
                                                   float* __restrict__ vmean,
                                                   float* __restrict__ qmean) {
  int d = blockIdx.x * 256 + threadIdx.x;
  int b = blockIdx.y;
  const float* x; const float* mk; float* out;
  if (blockIdx.z == 0) { x = v; mk = vmask; out = vmean; }
  else                 { x = q; mk = qmask; out = qmean; }
  const float* xp = x + ((size_t)b * TOK) * DM + d;
  const float* mp = mk + b * TOK;
  float s = 0.f, ms = 0.f;
#pragma unroll 4
  for (int r = 0; r < TOK; ++r) {
    float m = mp[r];
    ms += m;
    s += xp[(size_t)r * DM] * m;
  }
  out[b * DM + d] = s / ms;
}

// ---------------- transpose + cast weights: w[K,N] f32 -> wt[N,K] bf16 ----------------
// block (32,8); grid (N/32, K/32)
__global__ void transpose_cast_kernel(const float* __restrict__ w, short* __restrict__ wt,
                                      int K, int N) {
  __shared__ float tile[32][33];
  int n0 = blockIdx.x * 32, k0 = blockIdx.y * 32;
  int tx = threadIdx.x, ty = threadIdx.y;
#pragma unroll
  for (int i = 0; i < 32; i += 8)
    tile[ty + i][tx] = w[(size_t)(k0 + ty + i) * N + n0 + tx];
  __syncthreads();
#pragma unroll
  for (int i = 0; i < 32; i += 8)
    wt[(size_t)(n0 + ty + i) * K + k0 + tx] = f2bf(tile[tx][ty + i]);
}

// ---------------- gates: out = 1 + sigmoid(relu(mean) @ w + b) ----------------
// grid (4, B, 2); block 256. z=0: v4q (vmean, gates q). z=1: q4v (qmean, gates v).
__global__ __launch_bounds__(256) void gate_kernel(const float* __restrict__ vmean,
                                                   const float* __restrict__ qmean,
                                                   const float* __restrict__ v4q_w,
                                                   const float* __restrict__ v4q_b,
                                                   const float* __restrict__ q4v_w,
                                                   const float* __restrict__ q4v_b,
                                                   float* __restrict__ gate_q,
                                                   float* __restrict__ gate_v) {
  int n = blockIdx.x * 256 + threadIdx.x;
  int b = blockIdx.y;
  const float* mean; const float* w; const float* bias; float* out;
  if (blockIdx.z == 0) { mean = vmean; w = v4q_w; bias = v4q_b; out = gate_q; }
  else                 { mean = qmean; w = q4v_w; bias = q4v_b; out = gate_v; }
  float acc = bias[n];
  const float* mp = mean + b * DM;
#pragma unroll 4
  for (int k = 0; k < DM; ++k) {
    float mv = mp[k];
    mv = mv > 0.f ? mv : 0.f;
    acc += mv * w[(size_t)k * DM + n];
  }
  out[b * DM + n] = 1.f + 1.f / (1.f + __expf(-acc));
}

// ---------------- memory-token K rows ----------------
// grid 17 blocks, 1024 threads. b<16: kmem_v[b,d] = 32*m_v_k[d]*gate_v[b,d]; b==16: kmem_c[d]=32*m_c_k[d]
__global__ void kmem_kernel(const float* __restrict__ m_v_k, const float* __restrict__ m_c_k,
                            const float* __restrict__ gate_v,
                            float* __restrict__ kmem_v, float* __restrict__ kmem_c) {
  int d = threadIdx.x;
  int b = blockIdx.x;
  if (b < 16) kmem_v[b * DM + d] = 32.0f * m_v_k[d] * gate_v[b * DM + d];
  else        kmem_c[d] = 32.0f * m_c_k[d];
}

// ---------------- GEMM: C[M,N] = A[M,K] @ B[K,N] via BT[N,K], bf16 MFMA ----------------
// tile 128x128, BK=64, 256 threads (4 waves, 2x2 wave grid, each wave 64x64 = 4x4 frags)
// epilogue: val = acc + bias[n]; if gate && n<2048: *= gate[b][n&1023]; if rowmask: *= rowmask[b][tok];
// store bf16 to outB or f32 to outF.
__global__ __launch_bounds__(256) void gemm_kernel(const short* __restrict__ A,
                                                   const short* __restrict__ BT,
                                                   const float* __restrict__ bias,
                                                   const float* __restrict__ rowmask,
                                                   const float* __restrict__ gate,
                                                   short* __restrict__ outB,
                                                   float* __restrict__ outF,
                                                   int N, int K) {
  __shared__ short As[128 * 64];
  __shared__ short Bs[128 * 64];
  int m0 = blockIdx.y * 128, n0 = blockIdx.x * 128;
  int tid = threadIdx.x;
  int w = tid >> 6, l = tid & 63;
  int wr = w >> 1, wc = w & 1;
  int lg = l >> 4, lo = l & 15;

  f32x4 acc[4][4];
#pragma unroll
  for (int i = 0; i < 4; ++i)
#pragma unroll
    for (int j = 0; j < 4; ++j) acc[i][j] = fzero4();

  for (int k0 = 0; k0 < K; k0 += 64) {
#pragma unroll
    for (int i = 0; i < 4; ++i) {
      int chunk = i * 256 + tid;           // 1024 chunks of 8 bf16
      int row = chunk >> 3, cc = chunk & 7;
      s16x8 av = *(const s16x8*)(A + (size_t)(m0 + row) * K + k0 + cc * 8);
      *(s16x8*)(As + row * 64 + ((cc ^ (row & 7)) * 8)) = av;
      s16x8 bv = *(const s16x8*)(BT + (size_t)(n0 + row) * K + k0 + cc * 8);
      *(s16x8*)(Bs + row * 64 + ((cc ^ (row & 7)) * 8)) = bv;
    }
    __syncthreads();
#pragma unroll
    for (int ks = 0; ks < 2; ++ks) {
      int lc = ks * 4 + lg;
      s16x8 af[4], bfr[4];
#pragma unroll
      for (int i = 0; i < 4; ++i) {
        int ar = wr * 64 + i * 16 + lo;
        af[i] = *(const s16x8*)(As + ar * 64 + ((lc ^ (ar & 7)) * 8));
        int br = wc * 64 + i * 16 + lo;
        bfr[i] = *(const s16x8*)(Bs + br * 64 + ((lc ^ (br & 7)) * 8));
      }
#pragma unroll
      for (int i = 0; i < 4; ++i)
#pragma unroll
        for (int j = 0; j < 4; ++j)
          acc[i][j] = __builtin_amdgcn_mfma_f32_16x16x32_bf16(af[i], bfr[j], acc[i][j], 0, 0, 0);
    }
    __syncthreads();
  }

  int b = m0 >> 9;
#pragma unroll
  for (int i = 0; i < 4; ++i)
#pragma unroll
    for (int j = 0; j < 4; ++j) {
      int row = m0 + wr * 64 + i * 16 + (lg << 2);
      int col = n0 + wc * 64 + j * 16 + lo;
      float cs = 1.f;
      if (gate != nullptr && col < 2048) cs = gate[b * DM + (col & 1023)];
      float bv = bias[col];
#pragma unroll
      for (int r = 0; r < 4; ++r) {
        float val = acc[i][j][r] + bv;
        val *= cs;
        if (rowmask != nullptr) val *= rowmask[b * TOK + ((row + r) & 511)];
        if (outB != nullptr) outB[(size_t)(row + r) * N + col] = f2bf(val);
        else                 outF[(size_t)(row + r) * N + col] = val;
      }
    }
}

// ---------------- flash attention over KQV buffer ----------------
// kqv: [8192][3072] bf16 (K at col 0, Q at col 1024, V at col 2048; head h -> +h*128)
// grid (8, 8, 16) = (qtile, head, batch); block 256 (4 waves; wave w owns 16 q rows)
// kmem: f32 mem-token K row ([B,DM] stride kmem_bstride, or [DM] with stride 0), or null
// vmem: f32 mem-token V row [DM], or null. xin: original x f32. xu out: bf16(x + attn_out).
__global__ __launch_bounds__(256) void attn_kernel(const short* __restrict__ kqv,
                                                   const float* __restrict__ kmask,
                                                   const float* __restrict__ kmem,
                                                   int kmem_bstride,
                                                   const float* __restrict__ vmem,
                                                   const float* __restrict__ xin,
                                                   short* __restrict__ xu) {
  __shared__ short VT[128 * 40];     // V^T staged: VT[d][k], stride 40 (80B, 16B aligned)
  __shared__ short P[4][16 * 40];    // per-wave P[q][k], stride 40
  int qt = blockIdx.x, h = blockIdx.y, b = blockIdx.z;
  int tid = threadIdx.x;
  int w = tid >> 6, l = tid & 63;
  int lg = l >> 4, lo = l & 15;
  size_t rowbase = (size_t)b * TOK;
  int q0 = qt * 64 + w * 16;
  const int LDK = 3072;
  const float scale = 0.08838834764831845f;   // 1/sqrt(128)

  s16x8 qf[4];
#pragma unroll
  for (int c = 0; c < 4; ++c)
    qf[c] = *(const s16x8*)(kqv + (rowbase + q0 + lo) * LDK + 1024 + h * 128 + c * 32 + lg * 8);

  float mrow[4], lrow[4];
  f32x4 oacc[8];
#pragma unroll
  for (int c = 0; c < 8; ++c) oacc[c] = fzero4();

  if (kmem != nullptr) {
    const float* km = kmem + (size_t)b * kmem_bstride + h * 128;
    float part = 0.f;
#pragma unroll
    for (int c = 0; c < 4; ++c)
#pragma unroll
      for (int j = 0; j < 8; ++j)
        part += bf2f(qf[c][j]) * km[c * 32 + lg * 8 + j];
    part += __shfl_xor(part, 16);
    part += __shfl_xor(part, 32);
    float sm = part * scale;
#pragma unroll
    for (int r = 0; r < 4; ++r) { mrow[r] = __shfl(sm, lg * 4 + r); lrow[r] = 1.f; }
#pragma unroll
    for (int c = 0; c < 8; ++c) {
      float vv = vmem[h * 128 + c * 16 + lo];
      f32x4 o; o[0] = vv; o[1] = vv; o[2] = vv; o[3] = vv;
      oacc[c] = o;
    }
  } else {
#pragma unroll
    for (int r = 0; r < 4; ++r) { mrow[r] = -3.0e38f; lrow[r] = 0.f; }
  }

  for (int kt = 0; kt < 16; ++kt) {
    __syncthreads();   // prior PV reads of VT done
    // stage V^T tile (rows kt*32..+31 of V head-slice)
#pragma unroll
    for (int i = 0; i < 2; ++i) {
      int chunk = i * 256 + tid;           // 512 chunks of 8
      int r = chunk >> 4, c8 = chunk & 15;
      s16x8 vv = *(const s16x8*)(kqv + (rowbase + kt * 32 + r) * LDK + 2048 + h * 128 + c8 * 8);
#pragma unroll
      for (int j = 0; j < 8; ++j)
        VT[(c8 * 8 + j) * 40 + r] = vv[j];
    }
    __syncthreads();

    // QK^T: S[16q x 32k]
    f32x4 s0 = fzero4(), s1 = fzero4();
#pragma unroll
    for (int c = 0; c < 4; ++c) {
      s16x8 kf0 = *(const s16x8*)(kqv + (rowbase + kt * 32 + lo) * LDK + h * 128 + c * 32 + lg * 8);
      s16x8 kf1 = *(const s16x8*)(kqv + (rowbase + kt * 32 + 16 + lo) * LDK + h * 128 + c * 32 + lg * 8);
      s0 = __builtin_amdgcn_mfma_f32_16x16x32_bf16(qf[c], kf0, s0, 0, 0, 0);
      s1 = __builtin_amdgcn_mfma_f32_16x16x32_bf16(qf[c], kf1, s1, 0, 0, 0);
    }
    float km0 = kmask[b * TOK + kt * 32 + lo];
    float km1 = kmask[b * TOK + kt * 32 + 16 + lo];
    float fr[4];
#pragma unroll
    for (int r = 0; r < 4; ++r) {
      float a0 = ((km0 == 0.f) ? -1e9f : s0[r]) * scale;
      float a1 = ((km1 == 0.f) ? -1e9f : s1[r]) * scale;
      float mx = fmaxf(a0, a1);
      mx = fmaxf(mx, __shfl_xor(mx, 1));
      mx = fmaxf(mx, __shfl_xor(mx, 2));
      mx = fmaxf(mx, __shfl_xor(mx, 4));
      mx = fmaxf(mx, __shfl_xor(mx, 8));
      float nm = fmaxf(mrow[r], mx);
      float p0 = __expf(a0 - nm);
      float p1 = __expf(a1 - nm);
      s0[r] = p0; s1[r] = p1;
      float rs = p0 + p1;
      rs += __shfl_xor(rs, 1);
      rs += __shfl_xor(rs, 2);
      rs += __shfl_xor(rs, 4);
      rs += __shfl_xor(rs, 8);
      float f = __expf(mrow[r] - nm);
      lrow[r] = lrow[r] * f + rs;
      mrow[r] = nm;
      fr[r] = f;
    }
#pragma unroll
    for (int c = 0; c < 8; ++c)
#pragma unroll
      for (int r = 0; r < 4; ++r) oacc[c][r] *= fr[r];

    short* pw = &P[w][0];
#pragma unroll
    for (int r = 0; r < 4; ++r) {
      pw[(lg * 4 + r) * 40 + lo]      = f2bf(s0[r]);
      pw[(lg * 4 + r) * 40 + 16 + lo] = f2bf(s1[r]);
    }
    __syncthreads();   // P visible (and VT still valid)

    // PV: O[16q x 128d] += P[16q x 32k] @ V[32k x 128d]
    s16x8 pf = *(const s16x8*)(pw + lo * 40 + lg * 8);
#pragma unroll
    for (int c = 0; c < 8; ++c) {
      s16x8 vf = *(const s16x8*)(VT + (c * 16 + lo) * 40 + lg * 8);
      oacc[c] = __builtin_amdgcn_mfma_f32_16x16x32_bf16(pf, vf, oacc[c], 0, 0, 0);
    }
  }

  float invl[4];
#pragma unroll
  for (int r = 0; r < 4; ++r) invl[r] = 1.f / lrow[r];
#pragma unroll
  for (int c = 0; c < 8; ++c)
#pragma unroll
    for (int r = 0; r < 4; ++r) {
      size_t row = rowbase + q0 + lg * 4 + r;
      int col = h * 128 + c * 16 + lo;
      float val = oacc[c][r] * invl[r] + xin[row * DM + col];
      xu[row * DM + col] = f2bf(val);
    }
}

// ---------------- launcher ----------------
extern "C" void kernel_launch(void* const* d_in, const int* in_sizes, int n_in,
                              void* d_out, int out_size, void* d_ws, size_t ws_size,
                              hipStream_t stream) {
  const float* v      = (const float*)d_in[0];
  const float* q      = (const float*)d_in[1];
  const float* c      = (const float*)d_in[2];
  const float* v_mask = (const float*)d_in[3];
  const float* q_mask = (const float*)d_in[4];
  const float* c_mask = (const float*)d_in[5];
  const float* v4q_w  = (const float*)d_in[6];
  const float* v4q_b  = (const float*)d_in[7];
  const float* q4v_w  = (const float*)d_in[8];
  const float* q4v_b  = (const float*)d_in[9];
  const float* v_lin_w = (const float*)d_in[10];
  const float* v_lin_b = (const float*)d_in[11];
  const float* q_lin_w = (const float*)d_in[12];
  const float* q_lin_b = (const float*)d_in[13];
  const float* c_lin_w = (const float*)d_in[14];
  const float* c_lin_b = (const float*)d_in[15];
  const float* m_v_k  = (const float*)d_in[16];
  const float* m_v_v  = (const float*)d_in[17];
  const float* m_c_k  = (const float*)d_in[18];
  const float* m_c_v  = (const float*)d_in[19];
  const float* v_out_w = (const float*)d_in[20];
  const float* v_out_b = (const float*)d_in[21];
  const float* q_out_w = (const float*)d_in[22];
  const float* q_out_b = (const float*)d_in[23];
  const float* c_out_w = (const float*)d_in[24];
  const float* c_out_b = (const float*)d_in[25];

  const size_t MB = 1024ull * 1024ull;
  char* ws = (char*)d_ws;
  // xbf_* reused as xu_* after trans GEMMs consume them
  short* xbf_v = (short*)(ws + 0 * MB);      // 16MB each
  short* xbf_q = (short*)(ws + 16 * MB);
  short* xbf_c = (short*)(ws + 32 * MB);
  short* wt_lin_v = (short*)(ws + 48 * MB);  // 6MB each
  short* wt_lin_q = (short*)(ws + 54 * MB);
  short* wt_lin_c = (short*)(ws + 60 * MB);
  short* wt_out_v = (short*)(ws + 66 * MB);  // 2MB each
  short* wt_out_q = (short*)(ws + 68 * MB);
  short* wt_out_c = (short*)(ws + 70 * MB);
  short* kqv_v = (short*)(ws + 72 * MB);     // 48MB each
  short* kqv_q = (short*)(ws + 120 * MB);
  short* kqv_c = (short*)(ws + 168 * MB);
  float* vmean  = (float*)(ws + 216 * MB);
  float* qmean  = vmean + 16 * 1024;
  float* gate_q = qmean + 16 * 1024;   // 1+sig(v4q): gates q's q/k
  float* gate_v = gate_q + 16 * 1024;  // 1+sig(q4v): gates v's q/k
  float* kmem_v = gate_v + 16 * 1024;
  float* kmem_c = kmem_v + 16 * 1024;

  // 1. relu-cast inputs to bf16
  cast_relu_kernel<<<4096, 256, 0, stream>>>(v, xbf_v);
  cast_relu_kernel<<<4096, 256, 0, stream>>>(q, xbf_q);
  cast_relu_kernel<<<4096, 256, 0, stream>>>(c, xbf_c);
  // 2. masked means
  mean_kernel<<<dim3(4, 16, 2), 256, 0, stream>>>(v, q, v_mask, q_mask, vmean, qmean);
  // 3. weight transposes (f32 [K,N] -> bf16 [N,K])
  transpose_cast_kernel<<<dim3(96, 32), dim3(32, 8), 0, stream>>>(v_lin_w, wt_lin_v, 1024, 3072);
  transpose_cast_kernel<<<dim3(96, 32), dim3(32, 8), 0, stream>>>(q_lin_w, wt_lin_q, 1024, 3072);
  transpose_cast_kernel<<<dim3(96, 32), dim3(32, 8), 0, stream>>>(c_lin_w, wt_lin_c, 1024, 3072);
  transpose_cast_kernel<<<dim3(32, 32), dim3(32, 8), 0, stream>>>(v_out_w, wt_out_v, 1024, 1024);
  transpose_cast_kernel<<<dim3(32, 32), dim3(32, 8), 0, stream>>>(q_out_w, wt_out_q, 1024, 1024);
  transpose_cast_kernel<<<dim3(32, 32), dim3(32, 8), 0, stream>>>(c_out_w, wt_out_c, 1024, 1024);
  // 4. gates
  gate_kernel<<<dim3(4, 16, 2), 256, 0, stream>>>(vmean, qmean, v4q_w, v4q_b, q4v_w, q4v_b,
                                                  gate_q, gate_v);
  // 5. memory-token K rows
  kmem_kernel<<<17, 1024, 0, stream>>>(m_v_k, m_c_k, gate_v, kmem_v, kmem_c);
  // 6. trans GEMMs -> KQV buffers (bf16), mask+gate in epilogue
  gemm_kernel<<<dim3(24, 64), 256, 0, stream>>>(xbf_v, wt_lin_v, v_lin_b, v_mask, gate_v,
                                                kqv_v, nullptr, 3072, 1024);
  gemm_kernel<<<dim3(24, 64), 256, 0, stream>>>(xbf_q, wt_lin_q, q_lin_b, q_mask, gate_q,
                                                kqv_q, nullptr, 3072, 1024);
  gemm_kernel<<<dim3(24, 64), 256, 0, stream>>>(xbf_c, wt_lin_c, c_lin_b, c_mask, nullptr,
                                                kqv_c, nullptr, 3072, 1024);
  // 7. attention -> xu = bf16(x + update)  (xu overlays xbf; trans GEMMs already consumed it)
  attn_kernel<<<dim3(8, 8, 16), 256, 0, stream>>>(kqv_v, v_mask, kmem_v, 1024, m_v_v, v, xbf_v);
  attn_kernel<<<dim3(8, 8, 16), 256, 0, stream>>>(kqv_q, q_mask, nullptr, 0, nullptr, q, xbf_q);
  attn_kernel<<<dim3(8, 8, 16), 256, 0, stream>>>(kqv_c, c_mask, kmem_c, 0, m_c_v, c, xbf_c);
  // 8. output GEMMs -> d_out (f32), tuple order v,q,c
  float* outp = (float*)d_out;
  gemm_kernel<<<dim3(8, 64), 256, 0, stream>>>(xbf_v, wt_out_v, v_out_b, nullptr, nullptr,
                                               nullptr, outp, 1024, 1024);
  gemm_kernel<<<dim3(8, 64), 256, 0, stream>>>(xbf_q, wt_out_q, q_out_b, nullptr, nullptr,
                                               nullptr, outp + 8388608, 1024, 1024);
  gemm_kernel<<<dim3(8, 64), 256, 0, stream>>>(xbf_c, wt_out_c, c_out_b, nullptr, nullptr,
                                               nullptr, outp + 16777216, 1024, 1024);
}

// Round 3
// 851.065 us; speedup vs baseline: 1.2351x; 1.2351x over previous
//
#include <hip/hip_runtime.h>
#include <stdint.h>

typedef __attribute__((ext_vector_type(8))) short s16x8;
typedef __attribute__((ext_vector_type(4))) float f32x4;

#define DM 1024
#define TOK 512
#define LDK 3072

static __device__ __forceinline__ float bf2f(short u) {
  union { unsigned int i; float f; } x;
  x.i = ((unsigned int)(unsigned short)u) << 16;
  return x.f;
}
static __device__ __forceinline__ short f2bf(float f) {
  union { float f; unsigned int i; } x; x.f = f;
  unsigned int r = x.i + 0x7FFFu + ((x.i >> 16) & 1u);
  return (short)(r >> 16);
}
static __device__ __forceinline__ f32x4 fzero4() {
  f32x4 z; z[0]=0.f; z[1]=0.f; z[2]=0.f; z[3]=0.f; return z;
}
static __device__ __forceinline__ void gl_lds16(const short* g, short* s) {
  __builtin_amdgcn_global_load_lds((const __attribute__((address_space(1))) void*)g,
                                   (__attribute__((address_space(3))) void*)s, 16, 0, 0);
}

#define MFMA(a, b, c) __builtin_amdgcn_mfma_f32_16x16x32_bf16(a, b, c, 0, 0, 0)

// ---------------- cast relu(x) f32 -> bf16 ----------------
__global__ __launch_bounds__(256) void cast_relu_kernel(const float* __restrict__ x,
                                                        short* __restrict__ xb) {
  size_t i = ((size_t)blockIdx.x * 256 + threadIdx.x) * 8;
  float4 v0 = *(const float4*)(x + i);
  float4 v1 = *(const float4*)(x + i + 4);
  s16x8 o;
  o[0] = f2bf(fmaxf(v0.x, 0.f)); o[1] = f2bf(fmaxf(v0.y, 0.f));
  o[2] = f2bf(fmaxf(v0.z, 0.f)); o[3] = f2bf(fmaxf(v0.w, 0.f));
  o[4] = f2bf(fmaxf(v1.x, 0.f)); o[5] = f2bf(fmaxf(v1.y, 0.f));
  o[6] = f2bf(fmaxf(v1.z, 0.f)); o[7] = f2bf(fmaxf(v1.w, 0.f));
  *(s16x8*)(xb + i) = o;
}

// ---------------- masked means ----------------
__global__ __launch_bounds__(256) void mean_kernel(const float* __restrict__ v,
                                                   const float* __restrict__ q,
                                                   const float* __restrict__ vmask,
                                                   const float* __restrict__ qmask,
                                                   float* __restrict__ vmean,
                                                   float* __restrict__ qmean) {
  int d = blockIdx.x * 256 + threadIdx.x;
  int b = blockIdx.y;
  const float* x; const float* mk; float* out;
  if (blockIdx.z == 0) { x = v; mk = vmask; out = vmean; }
  else                 { x = q; mk = qmask; out = qmean; }
  const float* xp = x + ((size_t)b * TOK) * DM + d;
  const float* mp = mk + b * TOK;
  float s = 0.f, ms = 0.f;
#pragma unroll 4
  for (int r = 0; r < TOK; ++r) {
    float m = mp[r];
    ms += m;
    s += xp[(size_t)r * DM] * m;
  }
  out[b * DM + d] = s / ms;
}

// ---------------- transpose + cast weights ----------------
__global__ void transpose_cast_kernel(const float* __restrict__ w, short* __restrict__ wt,
                                      int K, int N) {
  __shared__ float tile[32][33];
  int n0 = blockIdx.x * 32, k0 = blockIdx.y * 32;
  int tx = threadIdx.x, ty = threadIdx.y;
#pragma unroll
  for (int i = 0; i < 32; i += 8)
    tile[ty + i][tx] = w[(size_t)(k0 + ty + i) * N + n0 + tx];
  __syncthreads();
#pragma unroll
  for (int i = 0; i < 32; i += 8)
    wt[(size_t)(n0 + ty + i) * K + k0 + tx] = f2bf(tile[tx][ty + i]);
}

// ---------------- gates ----------------
__global__ __launch_bounds__(256) void gate_kernel(const float* __restrict__ vmean,
                                                   const float* __restrict__ qmean,
                                                   const float* __restrict__ v4q_w,
                                                   const float* __restrict__ v4q_b,
                                                   const float* __restrict__ q4v_w,
                                                   const float* __restrict__ q4v_b,
                                                   float* __restrict__ gate_q,
                                                   float* __restrict__ gate_v) {
  int n = blockIdx.x * 256 + threadIdx.x;
  int b = blockIdx.y;
  const float* mean; const float* w; const float* bias; float* out;
  if (blockIdx.z == 0) { mean = vmean; w = v4q_w; bias = v4q_b; out = gate_q; }
  else                 { mean = qmean; w = q4v_w; bias = q4v_b; out = gate_v; }
  float acc = bias[n];
  const float* mp = mean + b * DM;
#pragma unroll 4
  for (int k = 0; k < DM; ++k) {
    float mv = mp[k];
    mv = mv > 0.f ? mv : 0.f;
    acc += mv * w[(size_t)k * DM + n];
  }
  out[b * DM + n] = 1.f + 1.f / (1.f + __expf(-acc));
}

// ---------------- memory-token K rows ----------------
__global__ void kmem_kernel(const float* __restrict__ m_v_k, const float* __restrict__ m_c_k,
                            const float* __restrict__ gate_v,
                            float* __restrict__ kmem_v, float* __restrict__ kmem_c) {
  int d = threadIdx.x;
  int b = blockIdx.x;
  if (b < 16) kmem_v[b * DM + d] = 32.0f * m_v_k[d] * gate_v[b * DM + d];
  else        kmem_c[d] = 32.0f * m_c_k[d];
}

// ---------------- GEMM: C[M,N] = A[M,K] @ BT[N,K]^T, bf16 MFMA ----------------
__global__ __launch_bounds__(256) void gemm_kernel(const short* __restrict__ A,
                                                   const short* __restrict__ BT,
                                                   const float* __restrict__ bias,
                                                   const float* __restrict__ rowmask,
                                                   const float* __restrict__ gate,
                                                   short* __restrict__ outB,
                                                   float* __restrict__ outF,
                                                   int N, int K) {
  __shared__ short As[128 * 64];
  __shared__ short Bs[128 * 64];
  int m0 = blockIdx.x * 128, n0 = blockIdx.y * 128;
  int tid = threadIdx.x;
  int w = tid >> 6, l = tid & 63;
  int wr = w >> 1, wc = w & 1;
  int lg = l >> 4, lo = l & 15;

  f32x4 acc[4][4];
#pragma unroll
  for (int i = 0; i < 4; ++i)
#pragma unroll
    for (int j = 0; j < 4; ++j) acc[i][j] = fzero4();

  for (int k0 = 0; k0 < K; k0 += 64) {
    // async global->LDS staging, 16B/lane, pre-swizzled source / linear dest
#pragma unroll
    for (int i = 0; i < 4; ++i) {
      int c = (w * 4 + i) * 64 + l;
      int row = c >> 3;
      int cc = (l & 7) ^ (l >> 3);   // source chunk for dest slot (c&7) of row
      gl_lds16(A + (size_t)(m0 + row) * K + k0 + cc * 8, As + (w * 4 + i) * 512);
      gl_lds16(BT + (size_t)(n0 + row) * K + k0 + cc * 8, Bs + (w * 4 + i) * 512);
    }
    __syncthreads();
#pragma unroll
    for (int ks = 0; ks < 2; ++ks) {
      int lc = ks * 4 + lg;
      s16x8 af[4], bfr[4];
#pragma unroll
      for (int i = 0; i < 4; ++i) {
        int ar = wr * 64 + i * 16 + lo;
        af[i] = *(const s16x8*)(As + ar * 64 + ((lc ^ (ar & 7)) * 8));
        int br = wc * 64 + i * 16 + lo;
        bfr[i] = *(const s16x8*)(Bs + br * 64 + ((lc ^ (br & 7)) * 8));
      }
#pragma unroll
      for (int i = 0; i < 4; ++i)
#pragma unroll
        for (int j = 0; j < 4; ++j)
          acc[i][j] = MFMA(af[i], bfr[j], acc[i][j]);
    }
    __syncthreads();
  }

  int b = m0 >> 9;
#pragma unroll
  for (int i = 0; i < 4; ++i)
#pragma unroll
    for (int j = 0; j < 4; ++j) {
      int row = m0 + wr * 64 + i * 16 + (lg << 2);
      int col = n0 + wc * 64 + j * 16 + lo;
      float cs = 1.f;
      if (gate != nullptr && col < 2048) cs = gate[b * DM + (col & 1023)];
      float bv = bias[col];
#pragma unroll
      for (int r = 0; r < 4; ++r) {
        float val = acc[i][j][r] + bv;
        val *= cs;
        if (rowmask != nullptr) val *= rowmask[b * TOK + ((row + r) & 511)];
        if (outB != nullptr) outB[(size_t)(row + r) * N + col] = f2bf(val);
        else                 outF[(size_t)(row + r) * N + col] = val;
      }
    }
}

// ---------------- fused flash attention, all 3 modalities ----------------
struct AttnArgs {
  const short* kqv[3];
  const float* kmask[3];
  const float* kmem[3];
  const float* vmem[3];
  const float* xin[3];
  short* xu[3];
  int kmem_bstride[3];
};

// grid 3072 = 3 mods x 1024; block 256 = 4 waves x 16 q-rows. KVBLK=64.
// V staged in LDS as [k/8][d][k%8] (stride 1032 shorts): conflict-free scalar
// writes (banks 4*(l>>3)+(l&7)/2) and conflict-free b128 reads. K read direct
// from global (L2-resident; 8 qt-blocks of a (b,h) mapped to the same XCD).
__global__ __launch_bounds__(256) void attn_kernel(AttnArgs args) {
  __shared__ short Vs[8 * 1032];    // [k>>3][d][k&7], 16512 B
  __shared__ short Ps[4 * 16 * 72]; // per-wave P[q][k], stride 72
  int bid = blockIdx.x;
  int mod = bid >> 10;
  int r10 = bid & 1023;
  int x = r10 & 7, jj = r10 >> 3;
  int p = x * 16 + (jj & 15), qt = jj >> 4;   // 8 qt of a (b,h) share bid%8 -> same XCD
  int b = p >> 3, h = p & 7;

  const short* kqv  = args.kqv[mod];
  const float* kmask = args.kmask[mod];
  const float* kmem = args.kmem[mod];
  const float* vmem = args.vmem[mod];
  const float* xin  = args.xin[mod];
  short* xu = args.xu[mod];
  int kmem_bs = args.kmem_bstride[mod];

  int tid = threadIdx.x;
  int w = tid >> 6, l = tid & 63;
  int lg = l >> 4, lo = l & 15;
  size_t rowbase = (size_t)b * TOK;
  int q0 = qt * 64 + w * 16;
  const float scale = 0.08838834764831845f;   // 1/sqrt(128)
  short* Pw = Ps + w * (16 * 72);

  s16x8 qf[4];
#pragma unroll
  for (int c = 0; c < 4; ++c)
    qf[c] = *(const s16x8*)(kqv + (rowbase + q0 + lo) * LDK + 1024 + h * 128 + c * 32 + lg * 8);

  float mrow[4], lrow[4];
  f32x4 oacc[8];
#pragma unroll
  for (int c = 0; c < 8; ++c) oacc[c] = fzero4();

  if (kmem != nullptr) {
    const float* km = kmem + (size_t)b * kmem_bs + h * 128;
    float part = 0.f;
#pragma unroll
    for (int c = 0; c < 4; ++c)
#pragma unroll
      for (int j = 0; j < 8; ++j)
        part += bf2f(qf[c][j]) * km[c * 32 + lg * 8 + j];
    part += __shfl_xor(part, 16);
    part += __shfl_xor(part, 32);
    float sm = part * scale;
#pragma unroll
    for (int r = 0; r < 4; ++r) { mrow[r] = __shfl(sm, lg * 4 + r); lrow[r] = 1.f; }
#pragma unroll
    for (int c = 0; c < 8; ++c) {
      float vv = vmem[h * 128 + c * 16 + lo];
      f32x4 o; o[0] = vv; o[1] = vv; o[2] = vv; o[3] = vv;
      oacc[c] = o;
    }
  } else {
#pragma unroll
    for (int r = 0; r < 4; ++r) { mrow[r] = -3.0e38f; lrow[r] = 0.f; }
  }

#pragma unroll 1
  for (int kt = 0; kt < 8; ++kt) {
    __syncthreads();   // prior PV reads of Vs done in all waves
    // ---- stage V: lane l owns kv-row l, wave/iter pick the d-chunk ----
#pragma unroll
    for (int i = 0; i < 4; ++i) {
      int c8 = w * 4 + i;
      s16x8 vv = *(const s16x8*)(kqv + (rowbase + kt * 64 + l) * LDK + 2048 + h * 128 + c8 * 8);
      short* base = Vs + (l >> 3) * 1032 + c8 * 64 + (l & 7);
#pragma unroll
      for (int j = 0; j < 8; ++j) base[j * 8] = vv[j];
    }
    __syncthreads();

    // ---- QK^T: S[16q x 64k], K direct from global ----
    f32x4 s4[4];
#pragma unroll
    for (int sub = 0; sub < 4; ++sub) {
      f32x4 acc = fzero4();
#pragma unroll
      for (int cc = 0; cc < 4; ++cc) {
        s16x8 kf = *(const s16x8*)(kqv + (rowbase + kt * 64 + sub * 16 + lo) * LDK
                                   + h * 128 + cc * 32 + lg * 8);
        acc = MFMA(qf[cc], kf, acc);
      }
      s4[sub] = acc;
    }

    // ---- online softmax ----
    float km0 = kmask[b * TOK + kt * 64 + lo];
    float km1 = kmask[b * TOK + kt * 64 + 16 + lo];
    float km2 = kmask[b * TOK + kt * 64 + 32 + lo];
    float km3 = kmask[b * TOK + kt * 64 + 48 + lo];
    float fr[4];
    float pv[4][4];   // [r][sub]
#pragma unroll
    for (int r = 0; r < 4; ++r) {
      float a0 = ((km0 == 0.f) ? -1e9f : s4[0][r]) * scale;
      float a1 = ((km1 == 0.f) ? -1e9f : s4[1][r]) * scale;
      float a2 = ((km2 == 0.f) ? -1e9f : s4[2][r]) * scale;
      float a3 = ((km3 == 0.f) ? -1e9f : s4[3][r]) * scale;
      float mx = fmaxf(fmaxf(a0, a1), fmaxf(a2, a3));
      mx = fmaxf(mx, __shfl_xor(mx, 1));
      mx = fmaxf(mx, __shfl_xor(mx, 2));
      mx = fmaxf(mx, __shfl_xor(mx, 4));
      mx = fmaxf(mx, __shfl_xor(mx, 8));
      float nm = fmaxf(mrow[r], mx);
      float p0 = __expf(a0 - nm), p1 = __expf(a1 - nm);
      float p2 = __expf(a2 - nm), p3 = __expf(a3 - nm);
      float rs = (p0 + p1) + (p2 + p3);
      rs += __shfl_xor(rs, 1);
      rs += __shfl_xor(rs, 2);
      rs += __shfl_xor(rs, 4);
      rs += __shfl_xor(rs, 8);
      float f = __expf(mrow[r] - nm);
      lrow[r] = lrow[r] * f + rs;
      mrow[r] = nm;
      fr[r] = f;
      pv[r][0] = p0; pv[r][1] = p1; pv[r][2] = p2; pv[r][3] = p3;
    }
#pragma unroll
    for (int c = 0; c < 8; ++c)
#pragma unroll
      for (int r = 0; r < 4; ++r) oacc[c][r] *= fr[r];

    // ---- write P (per-wave region, bf16); banks 2-way max ----
#pragma unroll
    for (int sub = 0; sub < 4; ++sub)
#pragma unroll
      for (int r = 0; r < 4; ++r)
        Pw[(lg * 4 + r) * 72 + sub * 16 + lo] = f2bf(pv[r][sub]);

    // ---- PV: O[16q x 128d] += P[16 x 64] @ V[64 x 128] ----
    s16x8 pf0 = *(const s16x8*)(Pw + lo * 72 + lg * 8);        // k-window 0..31
    s16x8 pf1 = *(const s16x8*)(Pw + lo * 72 + 32 + lg * 8);   // k-window 32..63
#pragma unroll
    for (int c = 0; c < 8; ++c) {
      s16x8 vf0 = *(const s16x8*)(Vs + lg * 1032 + (c * 16 + lo) * 8);
      s16x8 vf1 = *(const s16x8*)(Vs + (4 + lg) * 1032 + (c * 16 + lo) * 8);
      oacc[c] = MFMA(pf0, vf0, oacc[c]);
      oacc[c] = MFMA(pf1, vf1, oacc[c]);
    }
  }

  float invl[4];
#pragma unroll
  for (int r = 0; r < 4; ++r) invl[r] = 1.f / lrow[r];
#pragma unroll
  for (int c = 0; c < 8; ++c)
#pragma unroll
    for (int r = 0; r < 4; ++r) {
      size_t row = rowbase + q0 + lg * 4 + r;
      int col = h * 128 + c * 16 + lo;
      float val = oacc[c][r] * invl[r] + xin[row * DM + col];
      xu[row * DM + col] = f2bf(val);
    }
}

// ---------------- launcher ----------------
extern "C" void kernel_launch(void* const* d_in, const int* in_sizes, int n_in,
                              void* d_out, int out_size, void* d_ws, size_t ws_size,
                              hipStream_t stream) {
  const float* v      = (const float*)d_in[0];
  const float* q      = (const float*)d_in[1];
  const float* c      = (const float*)d_in[2];
  const float* v_mask = (const float*)d_in[3];
  const float* q_mask = (const float*)d_in[4];
  const float* c_mask = (const float*)d_in[5];
  const float* v4q_w  = (const float*)d_in[6];
  const float* v4q_b  = (const float*)d_in[7];
  const float* q4v_w  = (const float*)d_in[8];
  const float* q4v_b  = (const float*)d_in[9];
  const float* v_lin_w = (const float*)d_in[10];
  const float* v_lin_b = (const float*)d_in[11];
  const float* q_lin_w = (const float*)d_in[12];
  const float* q_lin_b = (const float*)d_in[13];
  const float* c_lin_w = (const float*)d_in[14];
  const float* c_lin_b = (const float*)d_in[15];
  const float* m_v_k  = (const float*)d_in[16];
  const float* m_v_v  = (const float*)d_in[17];
  const float* m_c_k  = (const float*)d_in[18];
  const float* m_c_v  = (const float*)d_in[19];
  const float* v_out_w = (const float*)d_in[20];
  const float* v_out_b = (const float*)d_in[21];
  const float* q_out_w = (const float*)d_in[22];
  const float* q_out_b = (const float*)d_in[23];
  const float* c_out_w = (const float*)d_in[24];
  const float* c_out_b = (const float*)d_in[25];

  const size_t MB = 1024ull * 1024ull;
  char* ws = (char*)d_ws;
  short* xbf_v = (short*)(ws + 0 * MB);      // 16MB each; reused as xu after trans GEMMs
  short* xbf_q = (short*)(ws + 16 * MB);
  short* xbf_c = (short*)(ws + 32 * MB);
  short* wt_lin_v = (short*)(ws + 48 * MB);
  short* wt_lin_q = (short*)(ws + 54 * MB);
  short* wt_lin_c = (short*)(ws + 60 * MB);
  short* wt_out_v = (short*)(ws + 66 * MB);
  short* wt_out_q = (short*)(ws + 68 * MB);
  short* wt_out_c = (short*)(ws + 70 * MB);
  short* kqv_v = (short*)(ws + 72 * MB);     // 48MB each
  short* kqv_q = (short*)(ws + 120 * MB);
  short* kqv_c = (short*)(ws + 168 * MB);
  float* vmean  = (float*)(ws + 216 * MB);
  float* qmean  = vmean + 16 * 1024;
  float* gate_q = qmean + 16 * 1024;
  float* gate_v = gate_q + 16 * 1024;
  float* kmem_v = gate_v + 16 * 1024;
  float* kmem_c = kmem_v + 16 * 1024;

  cast_relu_kernel<<<4096, 256, 0, stream>>>(v, xbf_v);
  cast_relu_kernel<<<4096, 256, 0, stream>>>(q, xbf_q);
  cast_relu_kernel<<<4096, 256, 0, stream>>>(c, xbf_c);
  mean_kernel<<<dim3(4, 16, 2), 256, 0, stream>>>(v, q, v_mask, q_mask, vmean, qmean);
  transpose_cast_kernel<<<dim3(96, 32), dim3(32, 8), 0, stream>>>(v_lin_w, wt_lin_v, 1024, 3072);
  transpose_cast_kernel<<<dim3(96, 32), dim3(32, 8), 0, stream>>>(q_lin_w, wt_lin_q, 1024, 3072);
  transpose_cast_kernel<<<dim3(96, 32), dim3(32, 8), 0, stream>>>(c_lin_w, wt_lin_c, 1024, 3072);
  transpose_cast_kernel<<<dim3(32, 32), dim3(32, 8), 0, stream>>>(v_out_w, wt_out_v, 1024, 1024);
  transpose_cast_kernel<<<dim3(32, 32), dim3(32, 8), 0, stream>>>(q_out_w, wt_out_q, 1024, 1024);
  transpose_cast_kernel<<<dim3(32, 32), dim3(32, 8), 0, stream>>>(c_out_w, wt_out_c, 1024, 1024);
  gate_kernel<<<dim3(4, 16, 2), 256, 0, stream>>>(vmean, qmean, v4q_w, v4q_b, q4v_w, q4v_b,
                                                  gate_q, gate_v);
  kmem_kernel<<<17, 1024, 0, stream>>>(m_v_k, m_c_k, gate_v, kmem_v, kmem_c);

  gemm_kernel<<<dim3(64, 24), 256, 0, stream>>>(xbf_v, wt_lin_v, v_lin_b, v_mask, gate_v,
                                                kqv_v, nullptr, 3072, 1024);
  gemm_kernel<<<dim3(64, 24), 256, 0, stream>>>(xbf_q, wt_lin_q, q_lin_b, q_mask, gate_q,
                                                kqv_q, nullptr, 3072, 1024);
  gemm_kernel<<<dim3(64, 24), 256, 0, stream>>>(xbf_c, wt_lin_c, c_lin_b, c_mask, nullptr,
                                                kqv_c, nullptr, 3072, 1024);

  AttnArgs aa;
  aa.kqv[0] = kqv_v; aa.kqv[1] = kqv_q; aa.kqv[2] = kqv_c;
  aa.kmask[0] = v_mask; aa.kmask[1] = q_mask; aa.kmask[2] = c_mask;
  aa.kmem[0] = kmem_v; aa.kmem[1] = nullptr; aa.kmem[2] = kmem_c;
  aa.vmem[0] = m_v_v; aa.vmem[1] = nullptr; aa.vmem[2] = m_c_v;
  aa.xin[0] = v; aa.xin[1] = q; aa.xin[2] = c;
  aa.xu[0] = xbf_v; aa.xu[1] = xbf_q; aa.xu[2] = xbf_c;
  aa.kmem_bstride[0] = 1024; aa.kmem_bstride[1] = 0; aa.kmem_bstride[2] = 0;
  attn_kernel<<<3072, 256, 0, stream>>>(aa);

  float* outp = (float*)d_out;
  gemm_kernel<<<dim3(64, 8), 256, 0, stream>>>(xbf_v, wt_out_v, v_out_b, nullptr, nullptr,
                                               nullptr, outp, 1024, 1024);
  gemm_kernel<<<dim3(64, 8), 256, 0, stream>>>(xbf_q, wt_out_q, q_out_b, nullptr, nullptr,
                                               nullptr, outp + 8388608, 1024, 1024);
  gemm_kernel<<<dim3(64, 8), 256, 0, stream>>>(xbf_c, wt_out_c, c_out_b, nullptr, nullptr,
                                               nullptr, outp + 16777216, 1024, 1024);
}

// Round 4
// 768.717 us; speedup vs baseline: 1.3674x; 1.1071x over previous
//
#include <hip/hip_runtime.h>
#include <stdint.h>

typedef __attribute__((ext_vector_type(8))) short s16x8;
typedef __attribute__((ext_vector_type(4))) float f32x4;

#define DM 1024
#define TOK 512
#define LDK 3072

static __device__ __forceinline__ float bf2f(short u) {
  union { unsigned int i; float f; } x;
  x.i = ((unsigned int)(unsigned short)u) << 16;
  return x.f;
}
static __device__ __forceinline__ short f2bf(float f) {
  union { float f; unsigned int i; } x; x.f = f;
  unsigned int r = x.i + 0x7FFFu + ((x.i >> 16) & 1u);
  return (short)(r >> 16);
}
static __device__ __forceinline__ f32x4 fzero4() {
  f32x4 z; z[0]=0.f; z[1]=0.f; z[2]=0.f; z[3]=0.f; return z;
}
static __device__ __forceinline__ void gl_lds16(const short* g, short* s) {
  __builtin_amdgcn_global_load_lds((const __attribute__((address_space(1))) void*)g,
                                   (__attribute__((address_space(3))) void*)s, 16, 0, 0);
}

#define MFMA(a, b, c) __builtin_amdgcn_mfma_f32_16x16x32_bf16(a, b, c, 0, 0, 0)

// ---------------- cast relu(x) f32 -> bf16 ----------------
__global__ __launch_bounds__(256) void cast_relu_kernel(const float* __restrict__ x,
                                                        short* __restrict__ xb) {
  size_t i = ((size_t)blockIdx.x * 256 + threadIdx.x) * 8;
  float4 v0 = *(const float4*)(x + i);
  float4 v1 = *(const float4*)(x + i + 4);
  s16x8 o;
  o[0] = f2bf(fmaxf(v0.x, 0.f)); o[1] = f2bf(fmaxf(v0.y, 0.f));
  o[2] = f2bf(fmaxf(v0.z, 0.f)); o[3] = f2bf(fmaxf(v0.w, 0.f));
  o[4] = f2bf(fmaxf(v1.x, 0.f)); o[5] = f2bf(fmaxf(v1.y, 0.f));
  o[6] = f2bf(fmaxf(v1.z, 0.f)); o[7] = f2bf(fmaxf(v1.w, 0.f));
  *(s16x8*)(xb + i) = o;
}

// ---------------- masked means ----------------
__global__ __launch_bounds__(256) void mean_kernel(const float* __restrict__ v,
                                                   const float* __restrict__ q,
                                                   const float* __restrict__ vmask,
                                                   const float* __restrict__ qmask,
                                                   float* __restrict__ vmean,
                                                   float* __restrict__ qmean) {
  int d = blockIdx.x * 256 + threadIdx.x;
  int b = blockIdx.y;
  const float* x; const float* mk; float* out;
  if (blockIdx.z == 0) { x = v; mk = vmask; out = vmean; }
  else                 { x = q; mk = qmask; out = qmean; }
  const float* xp = x + ((size_t)b * TOK) * DM + d;
  const float* mp = mk + b * TOK;
  float s = 0.f, ms = 0.f;
#pragma unroll 4
  for (int r = 0; r < TOK; ++r) {
    float m = mp[r];
    ms += m;
    s += xp[(size_t)r * DM] * m;
  }
  out[b * DM + d] = s / ms;
}

// ---------------- transpose + cast weights ----------------
__global__ void transpose_cast_kernel(const float* __restrict__ w, short* __restrict__ wt,
                                      int K, int N) {
  __shared__ float tile[32][33];
  int n0 = blockIdx.x * 32, k0 = blockIdx.y * 32;
  int tx = threadIdx.x, ty = threadIdx.y;
#pragma unroll
  for (int i = 0; i < 32; i += 8)
    tile[ty + i][tx] = w[(size_t)(k0 + ty + i) * N + n0 + tx];
  __syncthreads();
#pragma unroll
  for (int i = 0; i < 32; i += 8)
    wt[(size_t)(n0 + ty + i) * K + k0 + tx] = f2bf(tile[tx][ty + i]);
}

// ---------------- gates ----------------
__global__ __launch_bounds__(256) void gate_kernel(const float* __restrict__ vmean,
                                                   const float* __restrict__ qmean,
                                                   const float* __restrict__ v4q_w,
                                                   const float* __restrict__ v4q_b,
                                                   const float* __restrict__ q4v_w,
                                                   const float* __restrict__ q4v_b,
                                                   float* __restrict__ gate_q,
                                                   float* __restrict__ gate_v) {
  int n = blockIdx.x * 256 + threadIdx.x;
  int b = blockIdx.y;
  const float* mean; const float* w; const float* bias; float* out;
  if (blockIdx.z == 0) { mean = vmean; w = v4q_w; bias = v4q_b; out = gate_q; }
  else                 { mean = qmean; w = q4v_w; bias = q4v_b; out = gate_v; }
  float acc = bias[n];
  const float* mp = mean + b * DM;
#pragma unroll 4
  for (int k = 0; k < DM; ++k) {
    float mv = mp[k];
    mv = mv > 0.f ? mv : 0.f;
    acc += mv * w[(size_t)k * DM + n];
  }
  out[b * DM + n] = 1.f + 1.f / (1.f + __expf(-acc));
}

// ---------------- memory-token K rows ----------------
__global__ void kmem_kernel(const float* __restrict__ m_v_k, const float* __restrict__ m_c_k,
                            const float* __restrict__ gate_v,
                            float* __restrict__ kmem_v, float* __restrict__ kmem_c) {
  int d = threadIdx.x;
  int b = blockIdx.x;
  if (b < 16) kmem_v[b * DM + d] = 32.0f * m_v_k[d] * gate_v[b * DM + d];
  else        kmem_c[d] = 32.0f * m_c_k[d];
}

// ---------------- GEMM: C[M,N] = A[M,K] @ BT[N,K]^T, bf16 MFMA ----------------
__global__ __launch_bounds__(256) void gemm_kernel(const short* __restrict__ A,
                                                   const short* __restrict__ BT,
                                                   const float* __restrict__ bias,
                                                   const float* __restrict__ rowmask,
                                                   const float* __restrict__ gate,
                                                   short* __restrict__ outB,
                                                   float* __restrict__ outF,
                                                   int N, int K) {
  __shared__ short As[128 * 64];
  __shared__ short Bs[128 * 64];
  int m0 = blockIdx.x * 128, n0 = blockIdx.y * 128;
  int tid = threadIdx.x;
  int w = tid >> 6, l = tid & 63;
  int wr = w >> 1, wc = w & 1;
  int lg = l >> 4, lo = l & 15;

  f32x4 acc[4][4];
#pragma unroll
  for (int i = 0; i < 4; ++i)
#pragma unroll
    for (int j = 0; j < 4; ++j) acc[i][j] = fzero4();

  for (int k0 = 0; k0 < K; k0 += 64) {
#pragma unroll
    for (int i = 0; i < 4; ++i) {
      int c = (w * 4 + i) * 64 + l;
      int row = c >> 3;
      int cc = (l & 7) ^ (l >> 3);
      gl_lds16(A + (size_t)(m0 + row) * K + k0 + cc * 8, As + (w * 4 + i) * 512);
      gl_lds16(BT + (size_t)(n0 + row) * K + k0 + cc * 8, Bs + (w * 4 + i) * 512);
    }
    __syncthreads();
#pragma unroll
    for (int ks = 0; ks < 2; ++ks) {
      int lc = ks * 4 + lg;
      s16x8 af[4], bfr[4];
#pragma unroll
      for (int i = 0; i < 4; ++i) {
        int ar = wr * 64 + i * 16 + lo;
        af[i] = *(const s16x8*)(As + ar * 64 + ((lc ^ (ar & 7)) * 8));
        int br = wc * 64 + i * 16 + lo;
        bfr[i] = *(const s16x8*)(Bs + br * 64 + ((lc ^ (br & 7)) * 8));
      }
#pragma unroll
      for (int i = 0; i < 4; ++i)
#pragma unroll
        for (int j = 0; j < 4; ++j)
          acc[i][j] = MFMA(af[i], bfr[j], acc[i][j]);
    }
    __syncthreads();
  }

  int b = m0 >> 9;
#pragma unroll
  for (int i = 0; i < 4; ++i)
#pragma unroll
    for (int j = 0; j < 4; ++j) {
      int row = m0 + wr * 64 + i * 16 + (lg << 2);
      int col = n0 + wc * 64 + j * 16 + lo;
      float cs = 1.f;
      if (gate != nullptr && col < 2048) cs = gate[b * DM + (col & 1023)];
      float bv = bias[col];
#pragma unroll
      for (int r = 0; r < 4; ++r) {
        float val = acc[i][j][r] + bv;
        val *= cs;
        if (rowmask != nullptr) val *= rowmask[b * TOK + ((row + r) & 511)];
        if (outB != nullptr) outB[(size_t)(row + r) * N + col] = f2bf(val);
        else                 outF[(size_t)(row + r) * N + col] = val;
      }
    }
}

// ---------------- fused flash attention, all 3 modalities ----------------
struct AttnArgs {
  const short* kqv[3];
  const float* kmask[3];
  const float* kmem[3];
  const float* vmem[3];
  const float* xin[3];
  short* xu[3];
  int kmem_bstride[3];
};

// grid 1536 = 3 mods x 512; block 512 = 8 waves x 16 q-rows (QBLK=128). KVBLK=64.
// K staged via global_load_lds (XOR-swizzled [64][128] tile, 2-way banks on read).
// V staged reg->LDS as [k/8][d][k%8] (stride 1032), prefetched one tile ahead.
__global__ __launch_bounds__(512) void attn_kernel(AttnArgs args) {
  __shared__ short Ks[64 * 128];    // 16384 B
  __shared__ short Vs[8 * 1032];    // 16512 B
  __shared__ short Ps[8 * 1152];    // 18432 B, per-wave P[q][k] stride 72
  int bid = blockIdx.x;
  int mod = bid >> 9;
  int r9 = bid & 511;
  int x = r9 & 7, jj = r9 >> 3;
  int p = x * 16 + (jj & 15), qt = jj >> 4;   // 4 qt of a (b,h) share bid%8 -> same XCD
  int b = p >> 3, h = p & 7;

  const short* kqv  = args.kqv[mod];
  const float* kmask = args.kmask[mod];
  const float* kmem = args.kmem[mod];
  const float* vmem = args.vmem[mod];
  const float* xin  = args.xin[mod];
  short* xu = args.xu[mod];
  int kmem_bs = args.kmem_bstride[mod];

  int tid = threadIdx.x;
  int w = tid >> 6, l = tid & 63;
  int lg = l >> 4, lo = l & 15;
  size_t rowbase = (size_t)b * TOK;
  int q0 = qt * 128 + w * 16;
  const float scale = 0.08838834764831845f;   // 1/sqrt(128)
  short* Pw = Ps + w * 1152;

  s16x8 qf[4];
#pragma unroll
  for (int c = 0; c < 4; ++c)
    qf[c] = *(const s16x8*)(kqv + (rowbase + q0 + lo) * LDK + 1024 + h * 128 + c * 32 + lg * 8);

  float mrow[4], lrow[4];
  f32x4 oacc[8];
#pragma unroll
  for (int c = 0; c < 8; ++c) oacc[c] = fzero4();

  if (kmem != nullptr) {
    const float* km = kmem + (size_t)b * kmem_bs + h * 128;
    float part = 0.f;
#pragma unroll
    for (int c = 0; c < 4; ++c)
#pragma unroll
      for (int j = 0; j < 8; ++j)
        part += bf2f(qf[c][j]) * km[c * 32 + lg * 8 + j];
    part += __shfl_xor(part, 16);
    part += __shfl_xor(part, 32);
    float sm = part * scale;
#pragma unroll
    for (int r = 0; r < 4; ++r) { mrow[r] = __shfl(sm, lg * 4 + r); lrow[r] = 1.f; }
#pragma unroll
    for (int c = 0; c < 8; ++c) {
      float vv = vmem[h * 128 + c * 16 + lo];
      f32x4 o; o[0] = vv; o[1] = vv; o[2] = vv; o[3] = vv;
      oacc[c] = o;
    }
  } else {
#pragma unroll
    for (int r = 0; r < 4; ++r) { mrow[r] = -3.0e38f; lrow[r] = 0.f; }
  }

  // V chunk ownership: chunk cI = i*512 + tid -> row rV = cI>>4, d-chunk c8 = cI&15
  int rV0 = tid >> 4, c8_0 = tid & 15;
  int rV1 = (512 + tid) >> 4, c8_1 = tid & 15;   // = 32 + rV0
  // prologue: prefetch V tile 0 into regs
  s16x8 vregA = *(const s16x8*)(kqv + (rowbase + rV0) * LDK + 2048 + h * 128 + c8_0 * 8);
  s16x8 vregB = *(const s16x8*)(kqv + (rowbase + rV1) * LDK + 2048 + h * 128 + c8_1 * 8);

#pragma unroll 1
  for (int kt = 0; kt < 8; ++kt) {
    __syncthreads();   // prior iter's LDS reads (Ks/Vs/Ps) done in all waves
    // ---- issue K stage (async gl_lds, swizzled source / linear dest) ----
#pragma unroll
    for (int i = 0; i < 2; ++i) {
      int inst = w * 2 + i;
      int row = inst * 4 + lg;
      int csrc = (l & 15) ^ (row & 7);
      gl_lds16(kqv + (rowbase + kt * 64 + row) * LDK + h * 128 + csrc * 8,
               Ks + inst * 512);
    }
    // ---- write prefetched V regs to LDS ----
    {
      short* baseA = Vs + (rV0 >> 3) * 1032 + c8_0 * 64 + (rV0 & 7);
      short* baseB = Vs + (rV1 >> 3) * 1032 + c8_1 * 64 + (rV1 & 7);
#pragma unroll
      for (int j = 0; j < 8; ++j) baseA[j * 8] = vregA[j];
#pragma unroll
      for (int j = 0; j < 8; ++j) baseB[j * 8] = vregB[j];
    }
    __syncthreads();   // K staged, V written

    // ---- prefetch next V tile into regs (latency hides under compute) ----
    if (kt < 7) {
      vregA = *(const s16x8*)(kqv + (rowbase + (kt + 1) * 64 + rV0) * LDK + 2048 + h * 128 + c8_0 * 8);
      vregB = *(const s16x8*)(kqv + (rowbase + (kt + 1) * 64 + rV1) * LDK + 2048 + h * 128 + c8_1 * 8);
    }

    // ---- QK^T: S[16q x 64k], K from LDS ----
    f32x4 s4[4];
#pragma unroll
    for (int sub = 0; sub < 4; ++sub) {
      f32x4 acc = fzero4();
      int krow = sub * 16 + lo;
#pragma unroll
      for (int cc = 0; cc < 4; ++cc) {
        s16x8 kf = *(const s16x8*)(Ks + krow * 128 + (((cc * 4 + lg) ^ (lo & 7)) * 8));
        acc = MFMA(qf[cc], kf, acc);
      }
      s4[sub] = acc;
    }

    // ---- online softmax ----
    float km0 = kmask[b * TOK + kt * 64 + lo];
    float km1 = kmask[b * TOK + kt * 64 + 16 + lo];
    float km2 = kmask[b * TOK + kt * 64 + 32 + lo];
    float km3 = kmask[b * TOK + kt * 64 + 48 + lo];
    float fr[4];
    float pv[4][4];   // [r][sub]
#pragma unroll
    for (int r = 0; r < 4; ++r) {
      float a0 = ((km0 == 0.f) ? -1e9f : s4[0][r]) * scale;
      float a1 = ((km1 == 0.f) ? -1e9f : s4[1][r]) * scale;
      float a2 = ((km2 == 0.f) ? -1e9f : s4[2][r]) * scale;
      float a3 = ((km3 == 0.f) ? -1e9f : s4[3][r]) * scale;
      float mx = fmaxf(fmaxf(a0, a1), fmaxf(a2, a3));
      mx = fmaxf(mx, __shfl_xor(mx, 1));
      mx = fmaxf(mx, __shfl_xor(mx, 2));
      mx = fmaxf(mx, __shfl_xor(mx, 4));
      mx = fmaxf(mx, __shfl_xor(mx, 8));
      float nm = fmaxf(mrow[r], mx);
      float p0 = __expf(a0 - nm), p1 = __expf(a1 - nm);
      float p2 = __expf(a2 - nm), p3 = __expf(a3 - nm);
      float rs = (p0 + p1) + (p2 + p3);
      rs += __shfl_xor(rs, 1);
      rs += __shfl_xor(rs, 2);
      rs += __shfl_xor(rs, 4);
      rs += __shfl_xor(rs, 8);
      float f = __expf(mrow[r] - nm);
      lrow[r] = lrow[r] * f + rs;
      mrow[r] = nm;
      fr[r] = f;
      pv[r][0] = p0; pv[r][1] = p1; pv[r][2] = p2; pv[r][3] = p3;
    }
#pragma unroll
    for (int c = 0; c < 8; ++c)
#pragma unroll
      for (int r = 0; r < 4; ++r) oacc[c][r] *= fr[r];

    // ---- write P (per-wave region) ----
#pragma unroll
    for (int sub = 0; sub < 4; ++sub)
#pragma unroll
      for (int r = 0; r < 4; ++r)
        Pw[(lg * 4 + r) * 72 + sub * 16 + lo] = f2bf(pv[r][sub]);

    // ---- PV: O[16q x 128d] += P[16 x 64] @ V[64 x 128] ----
    s16x8 pf0 = *(const s16x8*)(Pw + lo * 72 + lg * 8);
    s16x8 pf1 = *(const s16x8*)(Pw + lo * 72 + 32 + lg * 8);
#pragma unroll
    for (int c = 0; c < 8; ++c) {
      s16x8 vf0 = *(const s16x8*)(Vs + lg * 1032 + (c * 16 + lo) * 8);
      s16x8 vf1 = *(const s16x8*)(Vs + (4 + lg) * 1032 + (c * 16 + lo) * 8);
      oacc[c] = MFMA(pf0, vf0, oacc[c]);
      oacc[c] = MFMA(pf1, vf1, oacc[c]);
    }
  }

  float invl[4];
#pragma unroll
  for (int r = 0; r < 4; ++r) invl[r] = 1.f / lrow[r];
#pragma unroll
  for (int c = 0; c < 8; ++c)
#pragma unroll
    for (int r = 0; r < 4; ++r) {
      size_t row = rowbase + q0 + lg * 4 + r;
      int col = h * 128 + c * 16 + lo;
      float val = oacc[c][r] * invl[r] + xin[row * DM + col];
      xu[row * DM + col] = f2bf(val);
    }
}

// ---------------- launcher ----------------
extern "C" void kernel_launch(void* const* d_in, const int* in_sizes, int n_in,
                              void* d_out, int out_size, void* d_ws, size_t ws_size,
                              hipStream_t stream) {
  const float* v      = (const float*)d_in[0];
  const float* q      = (const float*)d_in[1];
  const float* c      = (const float*)d_in[2];
  const float* v_mask = (const float*)d_in[3];
  const float* q_mask = (const float*)d_in[4];
  const float* c_mask = (const float*)d_in[5];
  const float* v4q_w  = (const float*)d_in[6];
  const float* v4q_b  = (const float*)d_in[7];
  const float* q4v_w  = (const float*)d_in[8];
  const float* q4v_b  = (const float*)d_in[9];
  const float* v_lin_w = (const float*)d_in[10];
  const float* v_lin_b = (const float*)d_in[11];
  const float* q_lin_w = (const float*)d_in[12];
  const float* q_lin_b = (const float*)d_in[13];
  const float* c_lin_w = (const float*)d_in[14];
  const float* c_lin_b = (const float*)d_in[15];
  const float* m_v_k  = (const float*)d_in[16];
  const float* m_v_v  = (const float*)d_in[17];
  const float* m_c_k  = (const float*)d_in[18];
  const float* m_c_v  = (const float*)d_in[19];
  const float* v_out_w = (const float*)d_in[20];
  const float* v_out_b = (const float*)d_in[21];
  const float* q_out_w = (const float*)d_in[22];
  const float* q_out_b = (const float*)d_in[23];
  const float* c_out_w = (const float*)d_in[24];
  const float* c_out_b = (const float*)d_in[25];

  const size_t MB = 1024ull * 1024ull;
  char* ws = (char*)d_ws;
  short* xbf_v = (short*)(ws + 0 * MB);      // 16MB each; reused as xu after trans GEMMs
  short* xbf_q = (short*)(ws + 16 * MB);
  short* xbf_c = (short*)(ws + 32 * MB);
  short* wt_lin_v = (short*)(ws + 48 * MB);
  short* wt_lin_q = (short*)(ws + 54 * MB);
  short* wt_lin_c = (short*)(ws + 60 * MB);
  short* wt_out_v = (short*)(ws + 66 * MB);
  short* wt_out_q = (short*)(ws + 68 * MB);
  short* wt_out_c = (short*)(ws + 70 * MB);
  short* kqv_v = (short*)(ws + 72 * MB);     // 48MB each
  short* kqv_q = (short*)(ws + 120 * MB);
  short* kqv_c = (short*)(ws + 168 * MB);
  float* vmean  = (float*)(ws + 216 * MB);
  float* qmean  = vmean + 16 * 1024;
  float* gate_q = qmean + 16 * 1024;
  float* gate_v = gate_q + 16 * 1024;
  float* kmem_v = gate_v + 16 * 1024;
  float* kmem_c = kmem_v + 16 * 1024;

  cast_relu_kernel<<<4096, 256, 0, stream>>>(v, xbf_v);
  cast_relu_kernel<<<4096, 256, 0, stream>>>(q, xbf_q);
  cast_relu_kernel<<<4096, 256, 0, stream>>>(c, xbf_c);
  mean_kernel<<<dim3(4, 16, 2), 256, 0, stream>>>(v, q, v_mask, q_mask, vmean, qmean);
  transpose_cast_kernel<<<dim3(96, 32), dim3(32, 8), 0, stream>>>(v_lin_w, wt_lin_v, 1024, 3072);
  transpose_cast_kernel<<<dim3(96, 32), dim3(32, 8), 0, stream>>>(q_lin_w, wt_lin_q, 1024, 3072);
  transpose_cast_kernel<<<dim3(96, 32), dim3(32, 8), 0, stream>>>(c_lin_w, wt_lin_c, 1024, 3072);
  transpose_cast_kernel<<<dim3(32, 32), dim3(32, 8), 0, stream>>>(v_out_w, wt_out_v, 1024, 1024);
  transpose_cast_kernel<<<dim3(32, 32), dim3(32, 8), 0, stream>>>(q_out_w, wt_out_q, 1024, 1024);
  transpose_cast_kernel<<<dim3(32, 32), dim3(32, 8), 0, stream>>>(c_out_w, wt_out_c, 1024, 1024);
  gate_kernel<<<dim3(4, 16, 2), 256, 0, stream>>>(vmean, qmean, v4q_w, v4q_b, q4v_w, q4v_b,
                                                  gate_q, gate_v);
  kmem_kernel<<<17, 1024, 0, stream>>>(m_v_k, m_c_k, gate_v, kmem_v, kmem_c);

  gemm_kernel<<<dim3(64, 24), 256, 0, stream>>>(xbf_v, wt_lin_v, v_lin_b, v_mask, gate_v,
                                                kqv_v, nullptr, 3072, 1024);
  gemm_kernel<<<dim3(64, 24), 256, 0, stream>>>(xbf_q, wt_lin_q, q_lin_b, q_mask, gate_q,
                                                kqv_q, nullptr, 3072, 1024);
  gemm_kernel<<<dim3(64, 24), 256, 0, stream>>>(xbf_c, wt_lin_c, c_lin_b, c_mask, nullptr,
                                                kqv_c, nullptr, 3072, 1024);

  AttnArgs aa;
  aa.kqv[0] = kqv_v; aa.kqv[1] = kqv_q; aa.kqv[2] = kqv_c;
  aa.kmask[0] = v_mask; aa.kmask[1] = q_mask; aa.kmask[2] = c_mask;
  aa.kmem[0] = kmem_v; aa.kmem[1] = nullptr; aa.kmem[2] = kmem_c;
  aa.vmem[0] = m_v_v; aa.vmem[1] = nullptr; aa.vmem[2] = m_c_v;
  aa.xin[0] = v; aa.xin[1] = q; aa.xin[2] = c;
  aa.xu[0] = xbf_v; aa.xu[1] = xbf_q; aa.xu[2] = xbf_c;
  aa.kmem_bstride[0] = 1024; aa.kmem_bstride[1] = 0; aa.kmem_bstride[2] = 0;
  attn_kernel<<<1536, 512, 0, stream>>>(aa);

  float* outp = (float*)d_out;
  gemm_kernel<<<dim3(64, 8), 256, 0, stream>>>(xbf_v, wt_out_v, v_out_b, nullptr, nullptr,
                                               nullptr, outp, 1024, 1024);
  gemm_kernel<<<dim3(64, 8), 256, 0, stream>>>(xbf_q, wt_out_q, q_out_b, nullptr, nullptr,
                                               nullptr, outp + 8388608, 1024, 1024);
  gemm_kernel<<<dim3(64, 8), 256, 0, stream>>>(xbf_c, wt_out_c, c_out_b, nullptr, nullptr,
                                               nullptr, outp + 16777216, 1024, 1024);
}

// Round 5
// 712.881 us; speedup vs baseline: 1.4745x; 1.0783x over previous
//
#include <hip/hip_runtime.h>
#include <stdint.h>

typedef __attribute__((ext_vector_type(8))) short s16x8;
typedef __attribute__((ext_vector_type(4))) float f32x4;

#define DM 1024
#define TOK 512
#define LDK 3072

static __device__ __forceinline__ float bf2f(short u) {
  union { unsigned int i; float f; } x;
  x.i = ((unsigned int)(unsigned short)u) << 16;
  return x.f;
}
static __device__ __forceinline__ short f2bf(float f) {
  union { float f; unsigned int i; } x; x.f = f;
  unsigned int r = x.i + 0x7FFFu + ((x.i >> 16) & 1u);
  return (short)(r >> 16);
}
static __device__ __forceinline__ f32x4 fzero4() {
  f32x4 z; z[0]=0.f; z[1]=0.f; z[2]=0.f; z[3]=0.f; return z;
}
static __device__ __forceinline__ void gl_lds16(const short* g, short* s) {
  __builtin_amdgcn_global_load_lds((const __attribute__((address_space(1))) void*)g,
                                   (__attribute__((address_space(3))) void*)s, 16, 0, 0);
}

#define MFMA(a, b, c) __builtin_amdgcn_mfma_f32_16x16x32_bf16(a, b, c, 0, 0, 0)

// ---------------- cast relu(x) f32 -> bf16 ----------------
__global__ __launch_bounds__(256) void cast_relu_kernel(const float* __restrict__ x,
                                                        short* __restrict__ xb) {
  size_t i = ((size_t)blockIdx.x * 256 + threadIdx.x) * 8;
  float4 v0 = *(const float4*)(x + i);
  float4 v1 = *(const float4*)(x + i + 4);
  s16x8 o;
  o[0] = f2bf(fmaxf(v0.x, 0.f)); o[1] = f2bf(fmaxf(v0.y, 0.f));
  o[2] = f2bf(fmaxf(v0.z, 0.f)); o[3] = f2bf(fmaxf(v0.w, 0.f));
  o[4] = f2bf(fmaxf(v1.x, 0.f)); o[5] = f2bf(fmaxf(v1.y, 0.f));
  o[6] = f2bf(fmaxf(v1.z, 0.f)); o[7] = f2bf(fmaxf(v1.w, 0.f));
  *(s16x8*)(xb + i) = o;
}

// ---------------- masked means ----------------
__global__ __launch_bounds__(256) void mean_kernel(const float* __restrict__ v,
                                                   const float* __restrict__ q,
                                                   const float* __restrict__ vmask,
                                                   const float* __restrict__ qmask,
                                                   float* __restrict__ vmean,
                                                   float* __restrict__ qmean) {
  int d = blockIdx.x * 256 + threadIdx.x;
  int b = blockIdx.y;
  const float* x; const float* mk; float* out;
  if (blockIdx.z == 0) { x = v; mk = vmask; out = vmean; }
  else                 { x = q; mk = qmask; out = qmean; }
  const float* xp = x + ((size_t)b * TOK) * DM + d;
  const float* mp = mk + b * TOK;
  float s = 0.f, ms = 0.f;
#pragma unroll 4
  for (int r = 0; r < TOK; ++r) {
    float m = mp[r];
    ms += m;
    s += xp[(size_t)r * DM] * m;
  }
  out[b * DM + d] = s / ms;
}

// ---------------- transpose + cast weights ----------------
__global__ void transpose_cast_kernel(const float* __restrict__ w, short* __restrict__ wt,
                                      int K, int N) {
  __shared__ float tile[32][33];
  int n0 = blockIdx.x * 32, k0 = blockIdx.y * 32;
  int tx = threadIdx.x, ty = threadIdx.y;
#pragma unroll
  for (int i = 0; i < 32; i += 8)
    tile[ty + i][tx] = w[(size_t)(k0 + ty + i) * N + n0 + tx];
  __syncthreads();
#pragma unroll
  for (int i = 0; i < 32; i += 8)
    wt[(size_t)(n0 + ty + i) * K + k0 + tx] = f2bf(tile[tx][ty + i]);
}

// ---------------- gates ----------------
__global__ __launch_bounds__(256) void gate_kernel(const float* __restrict__ vmean,
                                                   const float* __restrict__ qmean,
                                                   const float* __restrict__ v4q_w,
                                                   const float* __restrict__ v4q_b,
                                                   const float* __restrict__ q4v_w,
                                                   const float* __restrict__ q4v_b,
                                                   float* __restrict__ gate_q,
                                                   float* __restrict__ gate_v) {
  int n = blockIdx.x * 256 + threadIdx.x;
  int b = blockIdx.y;
  const float* mean; const float* w; const float* bias; float* out;
  if (blockIdx.z == 0) { mean = vmean; w = v4q_w; bias = v4q_b; out = gate_q; }
  else                 { mean = qmean; w = q4v_w; bias = q4v_b; out = gate_v; }
  float acc = bias[n];
  const float* mp = mean + b * DM;
#pragma unroll 4
  for (int k = 0; k < DM; ++k) {
    float mv = mp[k];
    mv = mv > 0.f ? mv : 0.f;
    acc += mv * w[(size_t)k * DM + n];
  }
  out[b * DM + n] = 1.f + 1.f / (1.f + __expf(-acc));
}

// ---------------- memory-token K rows ----------------
__global__ void kmem_kernel(const float* __restrict__ m_v_k, const float* __restrict__ m_c_k,
                            const float* __restrict__ gate_v,
                            float* __restrict__ kmem_v, float* __restrict__ kmem_c) {
  int d = threadIdx.x;
  int b = blockIdx.x;
  if (b < 16) kmem_v[b * DM + d] = 32.0f * m_v_k[d] * gate_v[b * DM + d];
  else        kmem_c[d] = 32.0f * m_c_k[d];
}

// ---------------- GEMM: C[M,N] = A[M,K] @ BT[N,K]^T, bf16 MFMA ----------------
__global__ __launch_bounds__(256) void gemm_kernel(const short* __restrict__ A,
                                                   const short* __restrict__ BT,
                                                   const float* __restrict__ bias,
                                                   const float* __restrict__ rowmask,
                                                   const float* __restrict__ gate,
                                                   short* __restrict__ outB,
                                                   float* __restrict__ outF,
                                                   int N, int K) {
  __shared__ short As[128 * 64];
  __shared__ short Bs[128 * 64];
  int m0 = blockIdx.x * 128, n0 = blockIdx.y * 128;
  int tid = threadIdx.x;
  int w = tid >> 6, l = tid & 63;
  int wr = w >> 1, wc = w & 1;
  int lg = l >> 4, lo = l & 15;

  f32x4 acc[4][4];
#pragma unroll
  for (int i = 0; i < 4; ++i)
#pragma unroll
    for (int j = 0; j < 4; ++j) acc[i][j] = fzero4();

  for (int k0 = 0; k0 < K; k0 += 64) {
#pragma unroll
    for (int i = 0; i < 4; ++i) {
      int c = (w * 4 + i) * 64 + l;
      int row = c >> 3;
      int cc = (l & 7) ^ (l >> 3);
      gl_lds16(A + (size_t)(m0 + row) * K + k0 + cc * 8, As + (w * 4 + i) * 512);
      gl_lds16(BT + (size_t)(n0 + row) * K + k0 + cc * 8, Bs + (w * 4 + i) * 512);
    }
    __syncthreads();
#pragma unroll
    for (int ks = 0; ks < 2; ++ks) {
      int lc = ks * 4 + lg;
      s16x8 af[4], bfr[4];
#pragma unroll
      for (int i = 0; i < 4; ++i) {
        int ar = wr * 64 + i * 16 + lo;
        af[i] = *(const s16x8*)(As + ar * 64 + ((lc ^ (ar & 7)) * 8));
        int br = wc * 64 + i * 16 + lo;
        bfr[i] = *(const s16x8*)(Bs + br * 64 + ((lc ^ (br & 7)) * 8));
      }
#pragma unroll
      for (int i = 0; i < 4; ++i)
#pragma unroll
        for (int j = 0; j < 4; ++j)
          acc[i][j] = MFMA(af[i], bfr[j], acc[i][j]);
    }
    __syncthreads();
  }

  int b = m0 >> 9;
#pragma unroll
  for (int i = 0; i < 4; ++i)
#pragma unroll
    for (int j = 0; j < 4; ++j) {
      int row = m0 + wr * 64 + i * 16 + (lg << 2);
      int col = n0 + wc * 64 + j * 16 + lo;
      float cs = 1.f;
      if (gate != nullptr && col < 2048) cs = gate[b * DM + (col & 1023)];
      float bv = bias[col];
#pragma unroll
      for (int r = 0; r < 4; ++r) {
        float val = acc[i][j][r] + bv;
        val *= cs;
        if (rowmask != nullptr) val *= rowmask[b * TOK + ((row + r) & 511)];
        if (outB != nullptr) outB[(size_t)(row + r) * N + col] = f2bf(val);
        else                 outF[(size_t)(row + r) * N + col] = val;
      }
    }
}

// ---------------- fused flash attention, all 3 modalities ----------------
struct AttnArgs {
  const short* kqv[3];
  const float* kmask[3];
  const float* kmem[3];
  const float* vmem[3];
  const float* xin[3];
  short* xu[3];
  int kmem_bstride[3];
};

// grid 1536 = 3 mods x 512; block 512 = 8 waves x 16 q-rows (QBLK=128). KVBLK=64.
// K staged via global_load_lds (XOR-swizzled [64][128] tile, min-cycle reads).
// V staged reg->LDS as [k/8][d][k%8] (stride 1032): lane l owns kv-row l, wave w
// owns d-chunks {2w,2w+1} -> write banks 4*(l>>3)+(l&7)/2+4j = conflict-free
// (2 lanes/bank share one dword). Prefetched one tile ahead into registers.
__global__ __launch_bounds__(512) void attn_kernel(AttnArgs args) {
  __shared__ short Ks[64 * 128];    // 16384 B
  __shared__ short Vs[8 * 1032];    // 16512 B
  __shared__ short Ps[8 * 1152];    // 18432 B, per-wave P[q][k] stride 72
  int bid = blockIdx.x;
  int mod = bid >> 9;
  int r9 = bid & 511;
  int x = r9 & 7, jj = r9 >> 3;
  int p = x * 16 + (jj & 15), qt = jj >> 4;   // 4 qt of a (b,h) share bid%8 -> same XCD
  int b = p >> 3, h = p & 7;

  const short* kqv  = args.kqv[mod];
  const float* kmask = args.kmask[mod];
  const float* kmem = args.kmem[mod];
  const float* vmem = args.vmem[mod];
  const float* xin  = args.xin[mod];
  short* xu = args.xu[mod];
  int kmem_bs = args.kmem_bstride[mod];

  int tid = threadIdx.x;
  int w = tid >> 6, l = tid & 63;
  int lg = l >> 4, lo = l & 15;
  size_t rowbase = (size_t)b * TOK;
  int q0 = qt * 128 + w * 16;
  const float scale = 0.08838834764831845f;   // 1/sqrt(128)
  short* Pw = Ps + w * 1152;

  s16x8 qf[4];
#pragma unroll
  for (int c = 0; c < 4; ++c)
    qf[c] = *(const s16x8*)(kqv + (rowbase + q0 + lo) * LDK + 1024 + h * 128 + c * 32 + lg * 8);

  float mrow[4], lrow[4];
  f32x4 oacc[8];
#pragma unroll
  for (int c = 0; c < 8; ++c) oacc[c] = fzero4();

  if (kmem != nullptr) {
    const float* km = kmem + (size_t)b * kmem_bs + h * 128;
    float part = 0.f;
#pragma unroll
    for (int c = 0; c < 4; ++c)
#pragma unroll
      for (int j = 0; j < 8; ++j)
        part += bf2f(qf[c][j]) * km[c * 32 + lg * 8 + j];
    part += __shfl_xor(part, 16);
    part += __shfl_xor(part, 32);
    float sm = part * scale;
#pragma unroll
    for (int r = 0; r < 4; ++r) { mrow[r] = __shfl(sm, lg * 4 + r); lrow[r] = 1.f; }
#pragma unroll
    for (int c = 0; c < 8; ++c) {
      float vv = vmem[h * 128 + c * 16 + lo];
      f32x4 o; o[0] = vv; o[1] = vv; o[2] = vv; o[3] = vv;
      oacc[c] = o;
    }
  } else {
#pragma unroll
    for (int r = 0; r < 4; ++r) { mrow[r] = -3.0e38f; lrow[r] = 0.f; }
  }

  // V ownership (round-3 proven): lane l = kv-row l; wave w owns d-chunks 2w, 2w+1
  int c8A = 2 * w, c8B = 2 * w + 1;
  // prologue: prefetch V tile 0 into regs
  s16x8 vregA = *(const s16x8*)(kqv + (rowbase + l) * LDK + 2048 + h * 128 + c8A * 8);
  s16x8 vregB = *(const s16x8*)(kqv + (rowbase + l) * LDK + 2048 + h * 128 + c8B * 8);

#pragma unroll 1
  for (int kt = 0; kt < 8; ++kt) {
    __syncthreads();   // prior iter's LDS reads (Ks/Vs/Ps) done in all waves
    // ---- issue K stage (async gl_lds, swizzled source / linear dest) ----
#pragma unroll
    for (int i = 0; i < 2; ++i) {
      int inst = w * 2 + i;
      int row = inst * 4 + lg;
      int csrc = (l & 15) ^ (row & 7);
      gl_lds16(kqv + (rowbase + kt * 64 + row) * LDK + h * 128 + csrc * 8,
               Ks + inst * 512);
    }
    // ---- write prefetched V regs to LDS (conflict-free scalar writes) ----
    {
      short* baseA = Vs + (l >> 3) * 1032 + c8A * 64 + (l & 7);
      short* baseB = Vs + (l >> 3) * 1032 + c8B * 64 + (l & 7);
#pragma unroll
      for (int j = 0; j < 8; ++j) baseA[j * 8] = vregA[j];
#pragma unroll
      for (int j = 0; j < 8; ++j) baseB[j * 8] = vregB[j];
    }
    __syncthreads();   // K staged, V written

    // ---- prefetch next V tile into regs (latency hides under compute) ----
    if (kt < 7) {
      vregA = *(const s16x8*)(kqv + (rowbase + (kt + 1) * 64 + l) * LDK + 2048 + h * 128 + c8A * 8);
      vregB = *(const s16x8*)(kqv + (rowbase + (kt + 1) * 64 + l) * LDK + 2048 + h * 128 + c8B * 8);
    }

    // ---- QK^T: S[16q x 64k], K from LDS ----
    f32x4 s4[4];
#pragma unroll
    for (int sub = 0; sub < 4; ++sub) {
      f32x4 acc = fzero4();
      int krow = sub * 16 + lo;
#pragma unroll
      for (int cc = 0; cc < 4; ++cc) {
        s16x8 kf = *(const s16x8*)(Ks + krow * 128 + (((cc * 4 + lg) ^ (lo & 7)) * 8));
        acc = MFMA(qf[cc], kf, acc);
      }
      s4[sub] = acc;
    }

    // ---- online softmax ----
    float km0 = kmask[b * TOK + kt * 64 + lo];
    float km1 = kmask[b * TOK + kt * 64 + 16 + lo];
    float km2 = kmask[b * TOK + kt * 64 + 32 + lo];
    float km3 = kmask[b * TOK + kt * 64 + 48 + lo];
    float fr[4];
    float pv[4][4];   // [r][sub]
#pragma unroll
    for (int r = 0; r < 4; ++r) {
      float a0 = ((km0 == 0.f) ? -1e9f : s4[0][r]) * scale;
      float a1 = ((km1 == 0.f) ? -1e9f : s4[1][r]) * scale;
      float a2 = ((km2 == 0.f) ? -1e9f : s4[2][r]) * scale;
      float a3 = ((km3 == 0.f) ? -1e9f : s4[3][r]) * scale;
      float mx = fmaxf(fmaxf(a0, a1), fmaxf(a2, a3));
      mx = fmaxf(mx, __shfl_xor(mx, 1));
      mx = fmaxf(mx, __shfl_xor(mx, 2));
      mx = fmaxf(mx, __shfl_xor(mx, 4));
      mx = fmaxf(mx, __shfl_xor(mx, 8));
      float nm = fmaxf(mrow[r], mx);
      float p0 = __expf(a0 - nm), p1 = __expf(a1 - nm);
      float p2 = __expf(a2 - nm), p3 = __expf(a3 - nm);
      float rs = (p0 + p1) + (p2 + p3);
      rs += __shfl_xor(rs, 1);
      rs += __shfl_xor(rs, 2);
      rs += __shfl_xor(rs, 4);
      rs += __shfl_xor(rs, 8);
      float f = __expf(mrow[r] - nm);
      lrow[r] = lrow[r] * f + rs;
      mrow[r] = nm;
      fr[r] = f;
      pv[r][0] = p0; pv[r][1] = p1; pv[r][2] = p2; pv[r][3] = p3;
    }
#pragma unroll
    for (int c = 0; c < 8; ++c)
#pragma unroll
      for (int r = 0; r < 4; ++r) oacc[c][r] *= fr[r];

    // ---- write P (per-wave region) ----
#pragma unroll
    for (int sub = 0; sub < 4; ++sub)
#pragma unroll
      for (int r = 0; r < 4; ++r)
        Pw[(lg * 4 + r) * 72 + sub * 16 + lo] = f2bf(pv[r][sub]);

    // ---- PV: O[16q x 128d] += P[16 x 64] @ V[64 x 128] ----
    s16x8 pf0 = *(const s16x8*)(Pw + lo * 72 + lg * 8);
    s16x8 pf1 = *(const s16x8*)(Pw + lo * 72 + 32 + lg * 8);
#pragma unroll
    for (int c = 0; c < 8; ++c) {
      s16x8 vf0 = *(const s16x8*)(Vs + lg * 1032 + (c * 16 + lo) * 8);
      s16x8 vf1 = *(const s16x8*)(Vs + (4 + lg) * 1032 + (c * 16 + lo) * 8);
      oacc[c] = MFMA(pf0, vf0, oacc[c]);
      oacc[c] = MFMA(pf1, vf1, oacc[c]);
    }
  }

  float invl[4];
#pragma unroll
  for (int r = 0; r < 4; ++r) invl[r] = 1.f / lrow[r];
#pragma unroll
  for (int c = 0; c < 8; ++c)
#pragma unroll
    for (int r = 0; r < 4; ++r) {
      size_t row = rowbase + q0 + lg * 4 + r;
      int col = h * 128 + c * 16 + lo;
      float val = oacc[c][r] * invl[r] + xin[row * DM + col];
      xu[row * DM + col] = f2bf(val);
    }
}

// ---------------- launcher ----------------
extern "C" void kernel_launch(void* const* d_in, const int* in_sizes, int n_in,
                              void* d_out, int out_size, void* d_ws, size_t ws_size,
                              hipStream_t stream) {
  const float* v      = (const float*)d_in[0];
  const float* q      = (const float*)d_in[1];
  const float* c      = (const float*)d_in[2];
  const float* v_mask = (const float*)d_in[3];
  const float* q_mask = (const float*)d_in[4];
  const float* c_mask = (const float*)d_in[5];
  const float* v4q_w  = (const float*)d_in[6];
  const float* v4q_b  = (const float*)d_in[7];
  const float* q4v_w  = (const float*)d_in[8];
  const float* q4v_b  = (const float*)d_in[9];
  const float* v_lin_w = (const float*)d_in[10];
  const float* v_lin_b = (const float*)d_in[11];
  const float* q_lin_w = (const float*)d_in[12];
  const float* q_lin_b = (const float*)d_in[13];
  const float* c_lin_w = (const float*)d_in[14];
  const float* c_lin_b = (const float*)d_in[15];
  const float* m_v_k  = (const float*)d_in[16];
  const float* m_v_v  = (const float*)d_in[17];
  const float* m_c_k  = (const float*)d_in[18];
  const float* m_c_v  = (const float*)d_in[19];
  const float* v_out_w = (const float*)d_in[20];
  const float* v_out_b = (const float*)d_in[21];
  const float* q_out_w = (const float*)d_in[22];
  const float* q_out_b = (const float*)d_in[23];
  const float* c_out_w = (const float*)d_in[24];
  const float* c_out_b = (const float*)d_in[25];

  const size_t MB = 1024ull * 1024ull;
  char* ws = (char*)d_ws;
  short* xbf_v = (short*)(ws + 0 * MB);      // 16MB each; reused as xu after trans GEMMs
  short* xbf_q = (short*)(ws + 16 * MB);
  short* xbf_c = (short*)(ws + 32 * MB);
  short* wt_lin_v = (short*)(ws + 48 * MB);
  short* wt_lin_q = (short*)(ws + 54 * MB);
  short* wt_lin_c = (short*)(ws + 60 * MB);
  short* wt_out_v = (short*)(ws + 66 * MB);
  short* wt_out_q = (short*)(ws + 68 * MB);
  short* wt_out_c = (short*)(ws + 70 * MB);
  short* kqv_v = (short*)(ws + 72 * MB);     // 48MB each
  short* kqv_q = (short*)(ws + 120 * MB);
  short* kqv_c = (short*)(ws + 168 * MB);
  float* vmean  = (float*)(ws + 216 * MB);
  float* qmean  = vmean + 16 * 1024;
  float* gate_q = qmean + 16 * 1024;
  float* gate_v = gate_q + 16 * 1024;
  float* kmem_v = gate_v + 16 * 1024;
  float* kmem_c = kmem_v + 16 * 1024;

  cast_relu_kernel<<<4096, 256, 0, stream>>>(v, xbf_v);
  cast_relu_kernel<<<4096, 256, 0, stream>>>(q, xbf_q);
  cast_relu_kernel<<<4096, 256, 0, stream>>>(c, xbf_c);
  mean_kernel<<<dim3(4, 16, 2), 256, 0, stream>>>(v, q, v_mask, q_mask, vmean, qmean);
  transpose_cast_kernel<<<dim3(96, 32), dim3(32, 8), 0, stream>>>(v_lin_w, wt_lin_v, 1024, 3072);
  transpose_cast_kernel<<<dim3(96, 32), dim3(32, 8), 0, stream>>>(q_lin_w, wt_lin_q, 1024, 3072);
  transpose_cast_kernel<<<dim3(96, 32), dim3(32, 8), 0, stream>>>(c_lin_w, wt_lin_c, 1024, 3072);
  transpose_cast_kernel<<<dim3(32, 32), dim3(32, 8), 0, stream>>>(v_out_w, wt_out_v, 1024, 1024);
  transpose_cast_kernel<<<dim3(32, 32), dim3(32, 8), 0, stream>>>(q_out_w, wt_out_q, 1024, 1024);
  transpose_cast_kernel<<<dim3(32, 32), dim3(32, 8), 0, stream>>>(c_out_w, wt_out_c, 1024, 1024);
  gate_kernel<<<dim3(4, 16, 2), 256, 0, stream>>>(vmean, qmean, v4q_w, v4q_b, q4v_w, q4v_b,
                                                  gate_q, gate_v);
  kmem_kernel<<<17, 1024, 0, stream>>>(m_v_k, m_c_k, gate_v, kmem_v, kmem_c);

  gemm_kernel<<<dim3(64, 24), 256, 0, stream>>>(xbf_v, wt_lin_v, v_lin_b, v_mask, gate_v,
                                                kqv_v, nullptr, 3072, 1024);
  gemm_kernel<<<dim3(64, 24), 256, 0, stream>>>(xbf_q, wt_lin_q, q_lin_b, q_mask, gate_q,
                                                kqv_q, nullptr, 3072, 1024);
  gemm_kernel<<<dim3(64, 24), 256, 0, stream>>>(xbf_c, wt_lin_c, c_lin_b, c_mask, nullptr,
                                                kqv_c, nullptr, 3072, 1024);

  AttnArgs aa;
  aa.kqv[0] = kqv_v; aa.kqv[1] = kqv_q; aa.kqv[2] = kqv_c;
  aa.kmask[0] = v_mask; aa.kmask[1] = q_mask; aa.kmask[2] = c_mask;
  aa.kmem[0] = kmem_v; aa.kmem[1] = nullptr; aa.kmem[2] = kmem_c;
  aa.vmem[0] = m_v_v; aa.vmem[1] = nullptr; aa.vmem[2] = m_c_v;
  aa.xin[0] = v; aa.xin[1] = q; aa.xin[2] = c;
  aa.xu[0] = xbf_v; aa.xu[1] = xbf_q; aa.xu[2] = xbf_c;
  aa.kmem_bstride[0] = 1024; aa.kmem_bstride[1] = 0; aa.kmem_bstride[2] = 0;
  attn_kernel<<<1536, 512, 0, stream>>>(aa);

  float* outp = (float*)d_out;
  gemm_kernel<<<dim3(64, 8), 256, 0, stream>>>(xbf_v, wt_out_v, v_out_b, nullptr, nullptr,
                                               nullptr, outp, 1024, 1024);
  gemm_kernel<<<dim3(64, 8), 256, 0, stream>>>(xbf_q, wt_out_q, q_out_b, nullptr, nullptr,
                                               nullptr, outp + 8388608, 1024, 1024);
  gemm_kernel<<<dim3(64, 8), 256, 0, stream>>>(xbf_c, wt_out_c, c_out_b, nullptr, nullptr,
                                               nullptr, outp + 16777216, 1024, 1024);
}

// Round 6
// 664.554 us; speedup vs baseline: 1.5817x; 1.0727x over previous
//
#include <hip/hip_runtime.h>
#include <stdint.h>

typedef __attribute__((ext_vector_type(8))) short s16x8;
typedef __attribute__((ext_vector_type(4))) float f32x4;

#define DM 1024
#define TOK 512
#define LDK 3072

static __device__ __forceinline__ float bf2f(short u) {
  union { unsigned int i; float f; } x;
  x.i = ((unsigned int)(unsigned short)u) << 16;
  return x.f;
}
static __device__ __forceinline__ short f2bf(float f) {
  union { float f; unsigned int i; } x; x.f = f;
  unsigned int r = x.i + 0x7FFFu + ((x.i >> 16) & 1u);
  return (short)(r >> 16);
}
static __device__ __forceinline__ f32x4 fzero4() {
  f32x4 z; z[0]=0.f; z[1]=0.f; z[2]=0.f; z[3]=0.f; return z;
}
static __device__ __forceinline__ void gl_lds16(const short* g, short* s) {
  __builtin_amdgcn_global_load_lds((const __attribute__((address_space(1))) void*)g,
                                   (__attribute__((address_space(3))) void*)s, 16, 0, 0);
}

#define MFMA(a, b, c) __builtin_amdgcn_mfma_f32_16x16x32_bf16(a, b, c, 0, 0, 0)

// ---------------- cast relu(x) f32 -> bf16, 3 tensors in one dispatch ----------------
struct CastArgs { const float* x[3]; short* xb[3]; };
__global__ __launch_bounds__(256) void cast_relu_kernel(CastArgs a) {
  const float* x = a.x[blockIdx.y];
  short* xb = a.xb[blockIdx.y];
  size_t i = ((size_t)blockIdx.x * 256 + threadIdx.x) * 8;
  float4 v0 = *(const float4*)(x + i);
  float4 v1 = *(const float4*)(x + i + 4);
  s16x8 o;
  o[0] = f2bf(fmaxf(v0.x, 0.f)); o[1] = f2bf(fmaxf(v0.y, 0.f));
  o[2] = f2bf(fmaxf(v0.z, 0.f)); o[3] = f2bf(fmaxf(v0.w, 0.f));
  o[4] = f2bf(fmaxf(v1.x, 0.f)); o[5] = f2bf(fmaxf(v1.y, 0.f));
  o[6] = f2bf(fmaxf(v1.z, 0.f)); o[7] = f2bf(fmaxf(v1.w, 0.f));
  *(s16x8*)(xb + i) = o;
}

// ---------------- masked means ----------------
__global__ __launch_bounds__(256) void mean_kernel(const float* __restrict__ v,
                                                   const float* __restrict__ q,
                                                   const float* __restrict__ vmask,
                                                   const float* __restrict__ qmask,
                                                   float* __restrict__ vmean,
                                                   float* __restrict__ qmean) {
  int d = blockIdx.x * 256 + threadIdx.x;
  int b = blockIdx.y;
  const float* x; const float* mk; float* out;
  if (blockIdx.z == 0) { x = v; mk = vmask; out = vmean; }
  else                 { x = q; mk = qmask; out = qmean; }
  const float* xp = x + ((size_t)b * TOK) * DM + d;
  const float* mp = mk + b * TOK;
  float s = 0.f, ms = 0.f;
#pragma unroll 4
  for (int r = 0; r < TOK; ++r) {
    float m = mp[r];
    ms += m;
    s += xp[(size_t)r * DM] * m;
  }
  out[b * DM + d] = s / ms;
}

// ---------------- transpose + cast weights, 3 mats in one dispatch ----------------
struct TransArgs { const float* w[3]; short* wt[3]; };
__global__ void transpose_cast_kernel(TransArgs a, int K, int N) {
  __shared__ float tile[32][33];
  const float* w = a.w[blockIdx.z];
  short* wt = a.wt[blockIdx.z];
  int n0 = blockIdx.x * 32, k0 = blockIdx.y * 32;
  int tx = threadIdx.x, ty = threadIdx.y;
#pragma unroll
  for (int i = 0; i < 32; i += 8)
    tile[ty + i][tx] = w[(size_t)(k0 + ty + i) * N + n0 + tx];
  __syncthreads();
#pragma unroll
  for (int i = 0; i < 32; i += 8)
    wt[(size_t)(n0 + ty + i) * K + k0 + tx] = f2bf(tile[tx][ty + i]);
}

// ---------------- gates ----------------
__global__ __launch_bounds__(256) void gate_kernel(const float* __restrict__ vmean,
                                                   const float* __restrict__ qmean,
                                                   const float* __restrict__ v4q_w,
                                                   const float* __restrict__ v4q_b,
                                                   const float* __restrict__ q4v_w,
                                                   const float* __restrict__ q4v_b,
                                                   float* __restrict__ gate_q,
                                                   float* __restrict__ gate_v) {
  int n = blockIdx.x * 256 + threadIdx.x;
  int b = blockIdx.y;
  const float* mean; const float* w; const float* bias; float* out;
  if (blockIdx.z == 0) { mean = vmean; w = v4q_w; bias = v4q_b; out = gate_q; }
  else                 { mean = qmean; w = q4v_w; bias = q4v_b; out = gate_v; }
  float acc = bias[n];
  const float* mp = mean + b * DM;
#pragma unroll 4
  for (int k = 0; k < DM; ++k) {
    float mv = mp[k];
    mv = mv > 0.f ? mv : 0.f;
    acc += mv * w[(size_t)k * DM + n];
  }
  out[b * DM + n] = 1.f + 1.f / (1.f + __expf(-acc));
}

// ---------------- memory-token K rows ----------------
__global__ void kmem_kernel(const float* __restrict__ m_v_k, const float* __restrict__ m_c_k,
                            const float* __restrict__ gate_v,
                            float* __restrict__ kmem_v, float* __restrict__ kmem_c) {
  int d = threadIdx.x;
  int b = blockIdx.x;
  if (b < 16) kmem_v[b * DM + d] = 32.0f * m_v_k[d] * gate_v[b * DM + d];
  else        kmem_c[d] = 32.0f * m_c_k[d];
}

// ---------------- GEMM: C[M,N] = A[M,K] @ BT[N,K]^T, 3 problems via blockIdx.z ----------------
struct GemmArgs {
  const short* A[3]; const short* BT[3];
  const float* bias[3]; const float* rowmask[3]; const float* gate[3];
  short* outB[3]; float* outF[3];
};
__global__ __launch_bounds__(256) void gemm_kernel(GemmArgs ga, int N, int K) {
  __shared__ short As[128 * 64];
  __shared__ short Bs[128 * 64];
  int z = blockIdx.z;
  const short* A = ga.A[z];
  const short* BT = ga.BT[z];
  const float* bias = ga.bias[z];
  const float* rowmask = ga.rowmask[z];
  const float* gate = ga.gate[z];
  short* outB = ga.outB[z];
  float* outF = ga.outF[z];

  int m0 = blockIdx.x * 128, n0 = blockIdx.y * 128;
  int tid = threadIdx.x;
  int w = tid >> 6, l = tid & 63;
  int wr = w >> 1, wc = w & 1;
  int lg = l >> 4, lo = l & 15;

  f32x4 acc[4][4];
#pragma unroll
  for (int i = 0; i < 4; ++i)
#pragma unroll
    for (int j = 0; j < 4; ++j) acc[i][j] = fzero4();

  for (int k0 = 0; k0 < K; k0 += 64) {
#pragma unroll
    for (int i = 0; i < 4; ++i) {
      int c = (w * 4 + i) * 64 + l;
      int row = c >> 3;
      int cc = (l & 7) ^ (l >> 3);
      gl_lds16(A + (size_t)(m0 + row) * K + k0 + cc * 8, As + (w * 4 + i) * 512);
      gl_lds16(BT + (size_t)(n0 + row) * K + k0 + cc * 8, Bs + (w * 4 + i) * 512);
    }
    __syncthreads();
#pragma unroll
    for (int ks = 0; ks < 2; ++ks) {
      int lc = ks * 4 + lg;
      s16x8 af[4], bfr[4];
#pragma unroll
      for (int i = 0; i < 4; ++i) {
        int ar = wr * 64 + i * 16 + lo;
        af[i] = *(const s16x8*)(As + ar * 64 + ((lc ^ (ar & 7)) * 8));
        int br = wc * 64 + i * 16 + lo;
        bfr[i] = *(const s16x8*)(Bs + br * 64 + ((lc ^ (br & 7)) * 8));
      }
#pragma unroll
      for (int i = 0; i < 4; ++i)
#pragma unroll
        for (int j = 0; j < 4; ++j)
          acc[i][j] = MFMA(af[i], bfr[j], acc[i][j]);
    }
    __syncthreads();
  }

  int b = m0 >> 9;
#pragma unroll
  for (int i = 0; i < 4; ++i)
#pragma unroll
    for (int j = 0; j < 4; ++j) {
      int row = m0 + wr * 64 + i * 16 + (lg << 2);
      int col = n0 + wc * 64 + j * 16 + lo;
      float cs = 1.f;
      if (gate != nullptr && col < 2048) cs = gate[b * DM + (col & 1023)];
      float bv = bias[col];
#pragma unroll
      for (int r = 0; r < 4; ++r) {
        float val = acc[i][j][r] + bv;
        val *= cs;
        if (rowmask != nullptr) val *= rowmask[b * TOK + ((row + r) & 511)];
        if (outB != nullptr) outB[(size_t)(row + r) * N + col] = f2bf(val);
        else                 outF[(size_t)(row + r) * N + col] = val;
      }
    }
}

// ---------------- fused flash attention, all 3 modalities ----------------
struct AttnArgs {
  const short* kqv[3];
  const float* kmask[3];
  const float* kmem[3];
  const float* vmem[3];
  const float* xin[3];
  short* xu[3];
  int kmem_bstride[3];
};

// grid 1536 = 3 mods x 512; block 512 = 8 waves x 16 q-rows (QBLK=128). KVBLK=64.
// Softmax: shared per-lg-group max (valid upper bound for its 4 q-rows),
// l computed as a 9th MFMA output column (P @ ones), defer-max THR=8.
__global__ __launch_bounds__(512) void attn_kernel(AttnArgs args) {
  __shared__ short Ks[64 * 128];    // 16384 B
  __shared__ short Vs[8 * 1032];    // 16512 B, [k/8][d][k%8]
  __shared__ short Ps[8 * 1216];    // 19456 B, per-wave P[q][k] stride 76 (conflict-free writes)
  int bid = blockIdx.x;
  int mod = bid >> 9;
  int r9 = bid & 511;
  int x = r9 & 7, jj = r9 >> 3;
  int p = x * 16 + (jj & 15), qt = jj >> 4;   // 4 qt of a (b,h) share bid%8 -> same XCD
  int b = p >> 3, h = p & 7;

  const short* kqv  = args.kqv[mod];
  const float* kmask = args.kmask[mod];
  const float* kmem = args.kmem[mod];
  const float* vmem = args.vmem[mod];
  const float* xin  = args.xin[mod];
  short* xu = args.xu[mod];
  int kmem_bs = args.kmem_bstride[mod];

  int tid = threadIdx.x;
  int w = tid >> 6, l = tid & 63;
  int lg = l >> 4, lo = l & 15;
  size_t rowbase = (size_t)b * TOK;
  int q0 = qt * 128 + w * 16;
  const float scale = 0.08838834764831845f;   // 1/sqrt(128)
  short* Pw = Ps + w * 1216;

  s16x8 ones;
#pragma unroll
  for (int j = 0; j < 8; ++j) ones[j] = (short)0x3F80;   // bf16 1.0

  s16x8 qf[4];
#pragma unroll
  for (int c = 0; c < 4; ++c)
    qf[c] = *(const s16x8*)(kqv + (rowbase + q0 + lo) * LDK + 1024 + h * 128 + c * 32 + lg * 8);

  float m;            // running max, shared across this lane's 4 q-rows
  f32x4 oacc[9];      // [0..7] O columns, [8] = l (softmax denominator)
#pragma unroll
  for (int c = 0; c < 9; ++c) oacc[c] = fzero4();

  if (kmem != nullptr) {
    const float* km = kmem + (size_t)b * kmem_bs + h * 128;
    float part = 0.f;
#pragma unroll
    for (int c = 0; c < 4; ++c)
#pragma unroll
      for (int j = 0; j < 8; ++j)
        part += bf2f(qf[c][j]) * km[c * 32 + lg * 8 + j];
    part += __shfl_xor(part, 16);
    part += __shfl_xor(part, 32);
    float sm = part * scale;                 // lane lo (0..15) holds mem score of row q0+lo
    float sm4[4], w4[4];
#pragma unroll
    for (int r = 0; r < 4; ++r) sm4[r] = __shfl(sm, lg * 4 + r);
    m = fmaxf(fmaxf(sm4[0], sm4[1]), fmaxf(sm4[2], sm4[3]));
#pragma unroll
    for (int r = 0; r < 4; ++r) w4[r] = __expf(sm4[r] - m);
#pragma unroll
    for (int c = 0; c < 8; ++c) {
      float vv = vmem[h * 128 + c * 16 + lo];
#pragma unroll
      for (int r = 0; r < 4; ++r) oacc[c][r] = w4[r] * vv;
    }
#pragma unroll
    for (int r = 0; r < 4; ++r) oacc[8][r] = w4[r];
  } else {
    m = -3.0e38f;
  }

  // V ownership: lane l = kv-row l; wave w owns d-chunks 2w, 2w+1 (conflict-free writes)
  int c8A = 2 * w, c8B = 2 * w + 1;
  s16x8 vregA = *(const s16x8*)(kqv + (rowbase + l) * LDK + 2048 + h * 128 + c8A * 8);
  s16x8 vregB = *(const s16x8*)(kqv + (rowbase + l) * LDK + 2048 + h * 128 + c8B * 8);

#pragma unroll 1
  for (int kt = 0; kt < 8; ++kt) {
    __syncthreads();
    // ---- issue K stage (async gl_lds, swizzled source / linear dest) ----
#pragma unroll
    for (int i = 0; i < 2; ++i) {
      int inst = w * 2 + i;
      int row = inst * 4 + lg;
      int csrc = (l & 15) ^ (row & 7);
      gl_lds16(kqv + (rowbase + kt * 64 + row) * LDK + h * 128 + csrc * 8,
               Ks + inst * 512);
    }
    // ---- write prefetched V regs to LDS ----
    {
      short* baseA = Vs + (l >> 3) * 1032 + c8A * 64 + (l & 7);
      short* baseB = Vs + (l >> 3) * 1032 + c8B * 64 + (l & 7);
#pragma unroll
      for (int j = 0; j < 8; ++j) baseA[j * 8] = vregA[j];
#pragma unroll
      for (int j = 0; j < 8; ++j) baseB[j * 8] = vregB[j];
    }
    __syncthreads();

    // ---- prefetch next V tile ----
    if (kt < 7) {
      vregA = *(const s16x8*)(kqv + (rowbase + (kt + 1) * 64 + l) * LDK + 2048 + h * 128 + c8A * 8);
      vregB = *(const s16x8*)(kqv + (rowbase + (kt + 1) * 64 + l) * LDK + 2048 + h * 128 + c8B * 8);
    }

    // ---- QK^T: S[16q x 64k] ----
    f32x4 s4[4];
#pragma unroll
    for (int sub = 0; sub < 4; ++sub) {
      f32x4 acc = fzero4();
      int krow = sub * 16 + lo;
#pragma unroll
      for (int cc = 0; cc < 4; ++cc) {
        s16x8 kf = *(const s16x8*)(Ks + krow * 128 + (((cc * 4 + lg) ^ (lo & 7)) * 8));
        acc = MFMA(qf[cc], kf, acc);
      }
      s4[sub] = acc;
    }

    // ---- softmax: shared-max + defer-rescale ----
    float km0 = kmask[b * TOK + kt * 64 + lo];
    float km1 = kmask[b * TOK + kt * 64 + 16 + lo];
    float km2 = kmask[b * TOK + kt * 64 + 32 + lo];
    float km3 = kmask[b * TOK + kt * 64 + 48 + lo];
    float a[4][4];   // [sub][r]
    float pmax = -3.0e38f;
#pragma unroll
    for (int r = 0; r < 4; ++r) {
      a[0][r] = ((km0 == 0.f) ? -1e9f : s4[0][r]) * scale;
      a[1][r] = ((km1 == 0.f) ? -1e9f : s4[1][r]) * scale;
      a[2][r] = ((km2 == 0.f) ? -1e9f : s4[2][r]) * scale;
      a[3][r] = ((km3 == 0.f) ? -1e9f : s4[3][r]) * scale;
      pmax = fmaxf(pmax, fmaxf(fmaxf(a[0][r], a[1][r]), fmaxf(a[2][r], a[3][r])));
    }
    pmax = fmaxf(pmax, __shfl_xor(pmax, 1));
    pmax = fmaxf(pmax, __shfl_xor(pmax, 2));
    pmax = fmaxf(pmax, __shfl_xor(pmax, 4));
    pmax = fmaxf(pmax, __shfl_xor(pmax, 8));
    if (!__all(pmax - m <= 8.0f)) {
      float nm = fmaxf(m, pmax);
      float f = __expf(m - nm);
#pragma unroll
      for (int c = 0; c < 9; ++c)
#pragma unroll
        for (int r = 0; r < 4; ++r) oacc[c][r] *= f;
      m = nm;
    }

    // ---- write P (stride 76: conflict-free; values bounded by e^8) ----
#pragma unroll
    for (int sub = 0; sub < 4; ++sub)
#pragma unroll
      for (int r = 0; r < 4; ++r)
        Pw[(lg * 4 + r) * 76 + sub * 16 + lo] = f2bf(__expf(a[sub][r] - m));

    // ---- PV: O[16q x 128d] += P @ V; l column via P @ ones ----
    s16x8 pf0 = *(const s16x8*)(Pw + lo * 76 + lg * 8);
    s16x8 pf1 = *(const s16x8*)(Pw + lo * 76 + 32 + lg * 8);
#pragma unroll
    for (int c = 0; c < 8; ++c) {
      s16x8 vf0 = *(const s16x8*)(Vs + lg * 1032 + (c * 16 + lo) * 8);
      s16x8 vf1 = *(const s16x8*)(Vs + (4 + lg) * 1032 + (c * 16 + lo) * 8);
      oacc[c] = MFMA(pf0, vf0, oacc[c]);
      oacc[c] = MFMA(pf1, vf1, oacc[c]);
    }
    oacc[8] = MFMA(pf0, ones, oacc[8]);
    oacc[8] = MFMA(pf1, ones, oacc[8]);
  }

  float invl[4];
#pragma unroll
  for (int r = 0; r < 4; ++r) invl[r] = 1.f / oacc[8][r];
#pragma unroll
  for (int c = 0; c < 8; ++c)
#pragma unroll
    for (int r = 0; r < 4; ++r) {
      size_t row = rowbase + q0 + lg * 4 + r;
      int col = h * 128 + c * 16 + lo;
      float val = oacc[c][r] * invl[r] + xin[row * DM + col];
      xu[row * DM + col] = f2bf(val);
    }
}

// ---------------- launcher ----------------
extern "C" void kernel_launch(void* const* d_in, const int* in_sizes, int n_in,
                              void* d_out, int out_size, void* d_ws, size_t ws_size,
                              hipStream_t stream) {
  const float* v      = (const float*)d_in[0];
  const float* q      = (const float*)d_in[1];
  const float* c      = (const float*)d_in[2];
  const float* v_mask = (const float*)d_in[3];
  const float* q_mask = (const float*)d_in[4];
  const float* c_mask = (const float*)d_in[5];
  const float* v4q_w  = (const float*)d_in[6];
  const float* v4q_b  = (const float*)d_in[7];
  const float* q4v_w  = (const float*)d_in[8];
  const float* q4v_b  = (const float*)d_in[9];
  const float* v_lin_w = (const float*)d_in[10];
  const float* v_lin_b = (const float*)d_in[11];
  const float* q_lin_w = (const float*)d_in[12];
  const float* q_lin_b = (const float*)d_in[13];
  const float* c_lin_w = (const float*)d_in[14];
  const float* c_lin_b = (const float*)d_in[15];
  const float* m_v_k  = (const float*)d_in[16];
  const float* m_v_v  = (const float*)d_in[17];
  const float* m_c_k  = (const float*)d_in[18];
  const float* m_c_v  = (const float*)d_in[19];
  const float* v_out_w = (const float*)d_in[20];
  const float* v_out_b = (const float*)d_in[21];
  const float* q_out_w = (const float*)d_in[22];
  const float* q_out_b = (const float*)d_in[23];
  const float* c_out_w = (const float*)d_in[24];
  const float* c_out_b = (const float*)d_in[25];

  const size_t MB = 1024ull * 1024ull;
  char* ws = (char*)d_ws;
  short* xbf_v = (short*)(ws + 0 * MB);      // 16MB each; reused as xu after trans GEMMs
  short* xbf_q = (short*)(ws + 16 * MB);
  short* xbf_c = (short*)(ws + 32 * MB);
  short* wt_lin_v = (short*)(ws + 48 * MB);
  short* wt_lin_q = (short*)(ws + 54 * MB);
  short* wt_lin_c = (short*)(ws + 60 * MB);
  short* wt_out_v = (short*)(ws + 66 * MB);
  short* wt_out_q = (short*)(ws + 68 * MB);
  short* wt_out_c = (short*)(ws + 70 * MB);
  short* kqv_v = (short*)(ws + 72 * MB);     // 48MB each
  short* kqv_q = (short*)(ws + 120 * MB);
  short* kqv_c = (short*)(ws + 168 * MB);
  float* vmean  = (float*)(ws + 216 * MB);
  float* qmean  = vmean + 16 * 1024;
  float* gate_q = qmean + 16 * 1024;
  float* gate_v = gate_q + 16 * 1024;
  float* kmem_v = gate_v + 16 * 1024;
  float* kmem_c = kmem_v + 16 * 1024;

  CastArgs ca;
  ca.x[0] = v; ca.x[1] = q; ca.x[2] = c;
  ca.xb[0] = xbf_v; ca.xb[1] = xbf_q; ca.xb[2] = xbf_c;
  cast_relu_kernel<<<dim3(4096, 3), 256, 0, stream>>>(ca);
  mean_kernel<<<dim3(4, 16, 2), 256, 0, stream>>>(v, q, v_mask, q_mask, vmean, qmean);

  TransArgs tl;
  tl.w[0] = v_lin_w; tl.w[1] = q_lin_w; tl.w[2] = c_lin_w;
  tl.wt[0] = wt_lin_v; tl.wt[1] = wt_lin_q; tl.wt[2] = wt_lin_c;
  transpose_cast_kernel<<<dim3(96, 32, 3), dim3(32, 8), 0, stream>>>(tl, 1024, 3072);
  TransArgs to;
  to.w[0] = v_out_w; to.w[1] = q_out_w; to.w[2] = c_out_w;
  to.wt[0] = wt_out_v; to.wt[1] = wt_out_q; to.wt[2] = wt_out_c;
  transpose_cast_kernel<<<dim3(32, 32, 3), dim3(32, 8), 0, stream>>>(to, 1024, 1024);

  gate_kernel<<<dim3(4, 16, 2), 256, 0, stream>>>(vmean, qmean, v4q_w, v4q_b, q4v_w, q4v_b,
                                                  gate_q, gate_v);
  kmem_kernel<<<17, 1024, 0, stream>>>(m_v_k, m_c_k, gate_v, kmem_v, kmem_c);

  GemmArgs gt;
  gt.A[0] = xbf_v; gt.A[1] = xbf_q; gt.A[2] = xbf_c;
  gt.BT[0] = wt_lin_v; gt.BT[1] = wt_lin_q; gt.BT[2] = wt_lin_c;
  gt.bias[0] = v_lin_b; gt.bias[1] = q_lin_b; gt.bias[2] = c_lin_b;
  gt.rowmask[0] = v_mask; gt.rowmask[1] = q_mask; gt.rowmask[2] = c_mask;
  gt.gate[0] = gate_v; gt.gate[1] = gate_q; gt.gate[2] = nullptr;
  gt.outB[0] = kqv_v; gt.outB[1] = kqv_q; gt.outB[2] = kqv_c;
  gt.outF[0] = nullptr; gt.outF[1] = nullptr; gt.outF[2] = nullptr;
  gemm_kernel<<<dim3(64, 24, 3), 256, 0, stream>>>(gt, 3072, 1024);

  AttnArgs aa;
  aa.kqv[0] = kqv_v; aa.kqv[1] = kqv_q; aa.kqv[2] = kqv_c;
  aa.kmask[0] = v_mask; aa.kmask[1] = q_mask; aa.kmask[2] = c_mask;
  aa.kmem[0] = kmem_v; aa.kmem[1] = nullptr; aa.kmem[2] = kmem_c;
  aa.vmem[0] = m_v_v; aa.vmem[1] = nullptr; aa.vmem[2] = m_c_v;
  aa.xin[0] = v; aa.xin[1] = q; aa.xin[2] = c;
  aa.xu[0] = xbf_v; aa.xu[1] = xbf_q; aa.xu[2] = xbf_c;
  aa.kmem_bstride[0] = 1024; aa.kmem_bstride[1] = 0; aa.kmem_bstride[2] = 0;
  attn_kernel<<<1536, 512, 0, stream>>>(aa);

  float* outp = (float*)d_out;
  GemmArgs go;
  go.A[0] = xbf_v; go.A[1] = xbf_q; go.A[2] = xbf_c;
  go.BT[0] = wt_out_v; go.BT[1] = wt_out_q; go.BT[2] = wt_out_c;
  go.bias[0] = v_out_b; go.bias[1] = q_out_b; go.bias[2] = c_out_b;
  go.rowmask[0] = nullptr; go.rowmask[1] = nullptr; go.rowmask[2] = nullptr;
  go.gate[0] = nullptr; go.gate[1] = nullptr; go.gate[2] = nullptr;
  go.outB[0] = nullptr; go.outB[1] = nullptr; go.outB[2] = nullptr;
  go.outF[0] = outp; go.outF[1] = outp + 8388608; go.outF[2] = outp + 16777216;
  gemm_kernel<<<dim3(64, 8, 3), 256, 0, stream>>>(go, 1024, 1024);
}